// Round 15
// baseline (291.085 us; speedup 1.0000x reference)
//
#include <hip/hip_runtime.h>
#include <hip/hip_bf16.h>

#define SEQ 2048
#define DMODEL 2048
#define NHEAD 8
#define DHEAD 256

typedef _Float16 v8h __attribute__((ext_vector_type(8)));
typedef unsigned short v8u __attribute__((ext_vector_type(8)));
typedef float v4f __attribute__((ext_vector_type(4)));

__device__ __forceinline__ float b2f(unsigned short s) {
    return __uint_as_float(((unsigned)s) << 16);
}
__device__ __forceinline__ unsigned short f2b(float f) {
    unsigned u = __float_as_uint(f);
    u += 0x7fffu + ((u >> 16) & 1u);   // RNE
    return (unsigned short)(u >> 16);
}
__device__ __forceinline__ unsigned short f2h(float f) {
    _Float16 h = (_Float16)f;
    return __builtin_bit_cast(unsigned short, h);
}
__device__ __forceinline__ float h2f(unsigned short s) {
    return (float)__builtin_bit_cast(_Float16, s);
}

// --------------------------------------------------------------- streaming cvt
// (round-10 verbatim; per-block dtype detect measured free)
// [0,1024):    q,k -> fp16 (vectorized both dtypes)
// [1024,2048): v -> vT[h][d][s] fp16 (LDS 64x64 tile transpose)
__global__ __launch_bounds__(256) void k_cvt(const void* q, const void* k, const void* v,
                                             int* flag,
                                             unsigned short* qb, unsigned short* kb,
                                             unsigned short* vT) {
    __shared__ unsigned short tile[64][72];
    __shared__ int cnt;
    const int tid = threadIdx.x;
    const int b = blockIdx.x;

    if (tid == 0) cnt = 0;
    __syncthreads();
    {
        const unsigned short* qp = (const unsigned short*)q;
        int wild = 0;
        for (int i = tid; i < 2048; i += 256) {
            float x = b2f(qp[i]);
            float ax = fabsf(x);
            if (!(ax <= 100.0f) || (x != 0.0f && ax < 1e-6f)) wild++;
        }
        atomicAdd(&cnt, wild);
    }
    __syncthreads();
    const int bf = (cnt < 256) ? 1 : 0;
    if (b == 0 && tid == 0) *flag = bf;

    if (b < 1024) {
        size_t i0 = ((size_t)b * 256 + tid) * 16;
        if (bf) {
            const unsigned short* qp = (const unsigned short*)q;
            const unsigned short* kp = (const unsigned short*)k;
#pragma unroll
            for (int hlf = 0; hlf < 2; hlf++) {
                v8u uq = *(const v8u*)(qp + i0 + hlf * 8);
                v8u uk = *(const v8u*)(kp + i0 + hlf * 8);
                v8u oq, ok;
#pragma unroll
                for (int j = 0; j < 8; j++) { oq[j] = f2h(b2f(uq[j])); ok[j] = f2h(b2f(uk[j])); }
                *(v8u*)(qb + i0 + hlf * 8) = oq;
                *(v8u*)(kb + i0 + hlf * 8) = ok;
            }
        } else {
            const float* qf = (const float*)q;
            const float* kf = (const float*)k;
#pragma unroll
            for (int hlf = 0; hlf < 2; hlf++) {
                v4f q0 = *(const v4f*)(qf + i0 + hlf * 8);
                v4f q1 = *(const v4f*)(qf + i0 + hlf * 8 + 4);
                v4f k0 = *(const v4f*)(kf + i0 + hlf * 8);
                v4f k1 = *(const v4f*)(kf + i0 + hlf * 8 + 4);
                v8u oq, ok;
#pragma unroll
                for (int j = 0; j < 4; j++) {
                    oq[j] = f2h(q0[j]); oq[4 + j] = f2h(q1[j]);
                    ok[j] = f2h(k0[j]); ok[4 + j] = f2h(k1[j]);
                }
                *(v8u*)(qb + i0 + hlf * 8) = oq;
                *(v8u*)(kb + i0 + hlf * 8) = ok;
            }
        }
    } else {
        int b2 = b - 1024;
        int s0 = (b2 & 31) * 64, d0 = (b2 >> 5) * 64;
        int r = tid >> 2, c0 = (tid & 3) * 16;
        size_t base = (size_t)(s0 + r) * DMODEL + d0 + c0;
        if (bf) {
            const unsigned short* vp = (const unsigned short*)v;
            v8u a = *(const v8u*)(vp + base);
            v8u bb = *(const v8u*)(vp + base + 8);
#pragma unroll
            for (int j = 0; j < 8; j++) { tile[r][c0 + j] = f2h(b2f(a[j])); tile[r][c0 + 8 + j] = f2h(b2f(bb[j])); }
        } else {
            const float* vp = (const float*)v;
            v4f a0 = *(const v4f*)(vp + base);
            v4f a1 = *(const v4f*)(vp + base + 4);
            v4f a2 = *(const v4f*)(vp + base + 8);
            v4f a3 = *(const v4f*)(vp + base + 12);
#pragma unroll
            for (int j = 0; j < 4; j++) {
                tile[r][c0 + j] = f2h(a0[j]);      tile[r][c0 + 4 + j] = f2h(a1[j]);
                tile[r][c0 + 8 + j] = f2h(a2[j]);  tile[r][c0 + 12 + j] = f2h(a3[j]);
            }
        }
        __syncthreads();
        int dr = tid >> 2, sc0 = (tid & 3) * 16;
        v8u o0, o1;
#pragma unroll
        for (int j = 0; j < 8; j++) { o0[j] = tile[sc0 + j][dr]; o1[j] = tile[sc0 + 8 + j][dr]; }
        int head = d0 >> 8;
        int dh = (d0 & 255) + dr;
        size_t ob = ((size_t)head * DHEAD + dh) * SEQ + s0 + sc0;
        *(v8u*)(vT + ob) = o0;
        *(v8u*)(vT + ob + 8) = o1;
    }
}

// --------------------------------------------- gate pre-activations
// (round-10 verbatim: LDS-staged x, broadcast weights, atomicAdd into zeroed ipre/fpre)
__global__ __launch_bounds__(256) void k_gates(const unsigned short* __restrict__ qb,
                                               const unsigned short* __restrict__ kb,
                                               const void* __restrict__ v,
                                               const void* __restrict__ igk,
                                               const void* __restrict__ fgk,
                                               const int* flag,
                                               float* ipre, float* fpre) {
    __shared__ float x_lds[32][68];
    const int bf = *(volatile const int*)flag;
    const int s0 = blockIdx.x * 32;
    const int c  = blockIdx.y;
    const int tid = threadIdx.x;
    const int sl = tid >> 3, hh = tid & 7;
    const int rr = tid >> 3, j0 = (tid & 7) * 8;
    float accI = 0.f, accF = 0.f;
    const unsigned short* ik16 = (const unsigned short*)igk;
    const unsigned short* fk16 = (const unsigned short*)fgk;
    const float* ik32 = (const float*)igk;
    const float* fk32 = (const float*)fgk;

    for (int wd = 0; wd < 12; ++wd) {
        const int gd0 = c * 768 + wd * 64;
        __syncthreads();
        {
            float xv[8];
            if (gd0 < 4096) {
                const unsigned short* sp = (gd0 < 2048) ? qb : kb;
                const int off = (gd0 < 2048) ? gd0 : gd0 - 2048;
                v8u a = *(const v8u*)(sp + (size_t)(s0 + rr) * DMODEL + off + j0);
#pragma unroll
                for (int j = 0; j < 8; j++) xv[j] = h2f(a[j]);
            } else if (bf) {
                const unsigned short* vp = (const unsigned short*)v;
                v8u a = *(const v8u*)(vp + (size_t)(s0 + rr) * DMODEL + (gd0 - 4096) + j0);
#pragma unroll
                for (int j = 0; j < 8; j++) xv[j] = b2f(a[j]);
            } else {
                const float* vp = (const float*)v;
                const size_t base = (size_t)(s0 + rr) * DMODEL + (gd0 - 4096) + j0;
                v4f a0 = *(const v4f*)(vp + base);
                v4f a1 = *(const v4f*)(vp + base + 4);
#pragma unroll
                for (int j = 0; j < 4; j++) { xv[j] = a0[j]; xv[4 + j] = a1[j]; }
            }
#pragma unroll
            for (int j = 0; j < 8; j++) x_lds[rr][j0 + j] = xv[j];
        }
        __syncthreads();
        if (bf) {
#pragma unroll 8
            for (int j = 0; j < 64; j++) {
                float x = x_lds[sl][j];
                int wi = (gd0 + j) * NHEAD + hh;
                accI += x * b2f(ik16[wi]);
                accF += x * b2f(fk16[wi]);
            }
        } else {
#pragma unroll 8
            for (int j = 0; j < 64; j++) {
                float x = x_lds[sl][j];
                int wi = (gd0 + j) * NHEAD + hh;
                accI += x * ik32[wi];
                accF += x * fk32[wi];
            }
        }
    }
    atomicAdd(&ipre[hh * SEQ + s0 + sl], accI);
    atomicAdd(&fpre[hh * SEQ + s0 + sl], accF);
}

// ---------------- per-head scans (round-10 verbatim)
__global__ __launch_bounds__(256) void k_scan(const float* ipre, const float* fpre,
                                              const void* ib_, const void* fb_,
                                              const int* flag,
                                              float* a_g, float* amax_g, float* nfl_g) {
    __shared__ float wtot[4], wmax[4];
    int bf = *(volatile const int*)flag;
    int h = blockIdx.x, tid = threadIdx.x;
    int lane = tid & 63, wv = tid >> 6;
    float ib = bf ? b2f(((const unsigned short*)ib_)[h]) : ((const float*)ib_)[h];
    float fb = bf ? b2f(((const unsigned short*)fb_)[h]) : ((const float*)fb_)[h];
    int s0 = tid * 8;
    float lf[8], ip[8];
#pragma unroll
    for (int j = 0; j < 8; j++) {
        float fp = fpre[h * SEQ + s0 + j] + fb;
        lf[j] = fminf(fp, 0.0f) - log1pf(__expf(-fabsf(fp)));
        ip[j] = ipre[h * SEQ + s0 + j] + ib;
    }
    float cs[8]; float t = 0.f;
#pragma unroll
    for (int j = 0; j < 8; j++) { t += lf[j]; cs[j] = t; }
    float incl = t;
#pragma unroll
    for (int o = 1; o < 64; o <<= 1) {
        float n = __shfl_up(incl, o, 64);
        if (lane >= o) incl += n;
    }
    if (lane == 63) wtot[wv] = incl;
    __syncthreads();
    float wpre = 0.f;
#pragma unroll
    for (int i2 = 0; i2 < 4; i2++) if (i2 < wv) wpre += wtot[i2];
    float excl = wpre + incl - t;
    float cum[8], av[8];
#pragma unroll
    for (int j = 0; j < 8; j++) { cum[j] = excl + cs[j]; av[j] = ip[j] - cum[j]; }
    float mx = av[0];
#pragma unroll
    for (int j = 1; j < 8; j++) mx = fmaxf(mx, av[j]);
    float mincl = mx;
#pragma unroll
    for (int o = 1; o < 64; o <<= 1) {
        float n = __shfl_up(mincl, o, 64);
        if (lane >= o) mincl = fmaxf(mincl, n);
    }
    if (lane == 63) wmax[wv] = mincl;
    __syncthreads();
    float wpm = -3.0e38f;
#pragma unroll
    for (int i2 = 0; i2 < 4; i2++) if (i2 < wv) wpm = fmaxf(wpm, wmax[i2]);
    float up = __shfl_up(mincl, 1, 64);
    float run = fmaxf(wpm, (lane > 0) ? up : -3.0e38f);
#pragma unroll
    for (int j = 0; j < 8; j++) {
        run = fmaxf(run, av[j]);
        int s = s0 + j;
        a_g[h * SEQ + s]    = av[j];
        amax_g[h * SEQ + s] = run;
        float m = cum[j] + run;
        nfl_g[h * SEQ + s]  = __expf(fminf(fmaxf(-m, -60.f), 60.f));
    }
}

// --------------------------------------------------------------- main kernel
// Round-10 structure, LDS staging eliminated: Q/K fragments in registers (K
// prefetched one unit ahead), V fragments loaded direct from global vT (same
// 16-line/instr coalescing as the staged path; L2-hot per head), a/amax as
// per-lane register loads, normalizer B-operand is the constant (l15==0).
// Only P hi/lo stays in LDS (cross-wave). 2 barriers/unit unchanged.
__global__ __launch_bounds__(256, 3) void k_main(const unsigned short* __restrict__ qb,
                                                 const unsigned short* __restrict__ kb,
                                                 const unsigned short* __restrict__ vT,
                                                 const float* __restrict__ a_g,
                                                 const float* __restrict__ amax_g,
                                                 float* __restrict__ h_buf,
                                                 float* __restrict__ rs_buf) {
    __shared__ __align__(16) unsigned short P_lds[32][40];
    __shared__ __align__(16) unsigned short Plo_lds[32][40];

    const int h   = blockIdx.x;
    const int y   = blockIdx.y;        // quota index within head, 0..95
    const int tid = threadIdx.x;
    const int lane = tid & 63;
    const int w   = tid >> 6;          // wave 0..3
    const int l15 = lane & 15;
    const int qd  = (lane >> 4) & 3;   // quad
    const int hd0 = h * DHEAD;
    const int mw = w >> 1, nw = w & 1;
    const int qrow = mw * 16 + l15;    // Q fragment row within tile
    const int krow = nw * 16 + l15;    // K fragment row within s-block (= P col)
    const int coff = qd * 8;           // fragment col offset (shorts)

    // ---- quota: units [u, u_end) of this head's flattened triangle
    int u         = (y * 2080) / 96;
    int remaining = ((y + 1) * 2080) / 96 - u;
    int tile = (int)((sqrtf(8.0f * (float)u + 1.0f) - 1.0f) * 0.5f);
    while ((tile + 1) * (tile + 2) / 2 <= u) ++tile;
    while (tile * (tile + 1) / 2 > u) --tile;
    int js = u - tile * (tile + 1) / 2;
    bool needQ = true;

    const v4f vzero = {0.f, 0.f, 0.f, 0.f};
    v4f acc[2][4];
    v4f accN[2];
#pragma unroll
    for (int m = 0; m < 2; m++) {
        accN[m] = vzero;
#pragma unroll
        for (int n = 0; n < 4; n++) acc[m][n] = vzero;
    }

    // normalizer B-operand is a constant: ghost-ones row == (l15==0)
    v8h bN;
#pragma unroll
    for (int j = 0; j < 8; j++) bN[j] = (l15 == 0) ? (_Float16)1.0f : (_Float16)0.0f;

    v8u qr[8], kfr[8];
    v4f amax4;
    float av = 0.f, av2 = 0.f;
    {   // prefetch first unit's K fragment + a value
        const int s0 = js * 32;
        const unsigned short* ks = kb + (size_t)(s0 + krow) * DMODEL + hd0 + coff;
#pragma unroll
        for (int i = 0; i < 8; i++) kfr[i] = *(const v8u*)(ks + i * 32);
        av = a_g[h * SEQ + s0 + krow];
    }

    for (;;) {
        const int t0 = tile * 32;
        const int s0 = js * 32;
        if (needQ) {       // new tile: Q fragment + per-row stabilizer (registers)
            const unsigned short* src = qb + (size_t)(t0 + qrow) * DMODEL + hd0 + coff;
#pragma unroll
            for (int i = 0; i < 8; i++) qr[i] = *(const v8u*)(src + i * 32);
            amax4 = *(const v4f*)(amax_g + h * SEQ + t0 + mw * 16 + qd * 4);
            needQ = false;
        }

        // QK^T: pure-register MFMA (K prefetched last iteration)
        v4f c = vzero;
#pragma unroll
        for (int i = 0; i < 8; i++) {
            v8h a = __builtin_bit_cast(v8h, qr[i]);
            v8h b = __builtin_bit_cast(v8h, kfr[i]);
            c = __builtin_amdgcn_mfma_f32_16x16x32_f16(a, b, c, 0, 0, 0);
        }

        __syncthreads();   // previous unit's PV finished reading P_lds
        // decay weights + causal mask; write P as fp16 hi + lo residual
        {
            const bool diag = (js == tile);
            const int col = krow;
#pragma unroll
            for (int r = 0; r < 4; r++) {
                int row = mw * 16 + qd * 4 + r;
                float arg = fminf(av - amax4[r], 0.0f);
                float val = c[r] * 0.0625f * __expf(arg);   // 1/sqrt(256) folded here
                if (diag && col > row) val = 0.0f;
                unsigned short hi = f2h(val);
                float lo = val - h2f(hi);
                P_lds[row][col]   = hi;
                Plo_lds[row][col] = f2h(lo);
            }
        }
        __syncthreads();   // P ready for all waves

        // V fragments for THIS unit (direct from global, L2-hot), then
        // prefetch NEXT unit's K fragment + a value (latency hides under PV)
        v8u vfr[4];
#pragma unroll
        for (int nn = 0; nn < 4; nn++)
            vfr[nn] = *(const v8u*)(vT + (size_t)(hd0 + w * 64 + nn * 16 + l15) * SEQ + s0 + coff);

        int ntile = tile, njs = js + 1; bool nq = false;
        if (njs > tile) { ntile = tile + 1; njs = 0; nq = true; }
        if (remaining > 1) {
            const int ns0 = njs * 32;
            const unsigned short* ks = kb + (size_t)(ns0 + krow) * DMODEL + hd0 + coff;
#pragma unroll
            for (int i = 0; i < 8; i++) kfr[i] = *(const v8u*)(ks + i * 32);
            av2 = a_g[h * SEQ + ns0 + krow];
        }

        // P @ V (hi + lo): wave w owns output cols [w*64, w*64+64)
        v8h aH0 = *(const v8h*)&P_lds[l15][coff];
        v8h aH1 = *(const v8h*)&P_lds[16 + l15][coff];
        v8h aL0 = *(const v8h*)&Plo_lds[l15][coff];
        v8h aL1 = *(const v8h*)&Plo_lds[16 + l15][coff];
#pragma unroll
        for (int nn = 0; nn < 4; nn++) {
            v8h bV = __builtin_bit_cast(v8h, vfr[nn]);
            acc[0][nn] = __builtin_amdgcn_mfma_f32_16x16x32_f16(aH0, bV, acc[0][nn], 0, 0, 0);
            acc[0][nn] = __builtin_amdgcn_mfma_f32_16x16x32_f16(aL0, bV, acc[0][nn], 0, 0, 0);
            acc[1][nn] = __builtin_amdgcn_mfma_f32_16x16x32_f16(aH1, bV, acc[1][nn], 0, 0, 0);
            acc[1][nn] = __builtin_amdgcn_mfma_f32_16x16x32_f16(aL1, bV, acc[1][nn], 0, 0, 0);
        }
        if (w == 3) {   // constant ones-column normalizer (hi+lo)
            accN[0] = __builtin_amdgcn_mfma_f32_16x16x32_f16(aH0, bN, accN[0], 0, 0, 0);
            accN[0] = __builtin_amdgcn_mfma_f32_16x16x32_f16(aL0, bN, accN[0], 0, 0, 0);
            accN[1] = __builtin_amdgcn_mfma_f32_16x16x32_f16(aH1, bN, accN[1], 0, 0, 0);
            accN[1] = __builtin_amdgcn_mfma_f32_16x16x32_f16(aL1, bN, accN[1], 0, 0, 0);
        }

        // flush at tile end or quota end (raw partials; fire-and-forget atomics)
        if (js == tile || remaining == 1) {
#pragma unroll
            for (int m = 0; m < 2; m++)
#pragma unroll
                for (int r = 0; r < 4; r++) {
                    int row = t0 + m * 16 + qd * 4 + r;
#pragma unroll
                    for (int nn = 0; nn < 4; nn++) {
                        int col = hd0 + w * 64 + nn * 16 + l15;
                        atomicAdd(&h_buf[(size_t)row * DMODEL + col], acc[m][nn][r]);
                        acc[m][nn][r] = 0.f;
                    }
                    if (w == 3 && l15 == 0)
                        atomicAdd(&rs_buf[h * SEQ + row], accN[m][r]);
                    accN[m][r] = 0.f;
                }
        }
        if (--remaining == 0) break;
        tile = ntile; js = njs; needQ = nq; av = av2;
    }
}

// ------------------------------------- finish: normalizer scale + per-head LN
// (round-10 verbatim)
__global__ __launch_bounds__(256) void k_finish(const float* __restrict__ h_buf,
                                                const float* __restrict__ rs_buf,
                                                const float* __restrict__ nfl_g,
                                                const void* __restrict__ ow,
                                                const int* flag, void* out) {
    const int wv = threadIdx.x >> 6, lane = threadIdx.x & 63;
    const int rid = blockIdx.x * 4 + wv;       // 0..16383
    const int s = rid >> 3, h = rid & 7;
    const int bf = *(volatile const int*)flag;
    float rs  = rs_buf[h * SEQ + s];
    float nfl = nfl_g[h * SEQ + s];
    float sc  = 1.0f / (fmaxf(fabsf(rs), nfl) + 1e-6f);
    size_t base = (size_t)s * DMODEL + h * DHEAD + lane * 4;
    v4f hv = *(const v4f*)(h_buf + base);
#pragma unroll
    for (int j = 0; j < 4; j++) hv[j] *= sc;
    float sm = hv[0] + hv[1] + hv[2] + hv[3];
    float sq = hv[0] * hv[0] + hv[1] * hv[1] + hv[2] * hv[2] + hv[3] * hv[3];
#pragma unroll
    for (int m = 1; m < 64; m <<= 1) {
        sm += __shfl_xor(sm, m, 64);
        sq += __shfl_xor(sq, m, 64);
    }
    float mean = sm * (1.0f / 256.0f);
    float var  = fmaxf(sq * (1.0f / 256.0f) - mean * mean, 0.0f);
    float rstd = rsqrtf(var + 1e-6f);
    int gi = h * DHEAD + lane * 4;
    float gv[4];
    if (bf) {
        const unsigned short* gp = (const unsigned short*)ow;
#pragma unroll
        for (int j = 0; j < 4; j++) gv[j] = b2f(gp[gi + j]);
    } else {
        const float* gp = (const float*)ow;
#pragma unroll
        for (int j = 0; j < 4; j++) gv[j] = gp[gi + j];
    }
    if (bf) {
        unsigned short* o = (unsigned short*)out + base;
#pragma unroll
        for (int j = 0; j < 4; j++) o[j] = f2b((hv[j] - mean) * rstd * gv[j]);
    } else {
        float* o = (float*)out + base;
#pragma unroll
        for (int j = 0; j < 4; j++) o[j] = (hv[j] - mean) * rstd * gv[j];
    }
}

// ---------------------------------------------------------------------- host
extern "C" void kernel_launch(void* const* d_in, const int* in_sizes, int n_in,
                              void* d_out, int out_size, void* d_ws, size_t ws_size,
                              hipStream_t stream) {
    const void* q   = d_in[0];
    const void* k   = d_in[1];
    const void* v   = d_in[2];
    const void* igk = d_in[3];
    const void* igb = d_in[4];
    const void* fgk = d_in[5];
    const void* fgb = d_in[6];
    const void* ow  = d_in[7];

    char* ws = (char*)d_ws;
    int*   flag   = (int*)(ws + 0);
    // zeroed region (contiguous, one memset): ipre | fpre | rs_buf | h_buf
    float* ipre   = (float*)(ws + 1024);
    float* fpre   = ipre + NHEAD * SEQ;
    float* rs_buf = fpre + NHEAD * SEQ;
    float* h_buf  = rs_buf + NHEAD * SEQ;
    float* a_g    = h_buf + (size_t)SEQ * DMODEL;
    float* amax_g = a_g + NHEAD * SEQ;
    float* nfl_g  = amax_g + NHEAD * SEQ;
    unsigned short* qb = (unsigned short*)(nfl_g + NHEAD * SEQ);
    unsigned short* kb = qb + (size_t)SEQ * DMODEL;
    unsigned short* vT = kb + (size_t)SEQ * DMODEL;

    size_t zbytes = (size_t)(3 * NHEAD * SEQ) * 4 + (size_t)SEQ * DMODEL * 4;
    hipMemsetAsync(ipre, 0, zbytes, stream);
    k_cvt<<<2048, 256, 0, stream>>>(q, k, v, flag, qb, kb, vT);
    k_gates<<<dim3(64, 8), 256, 0, stream>>>(qb, kb, v, igk, fgk, flag, ipre, fpre);
    k_scan<<<8, 256, 0, stream>>>(ipre, fpre, igb, fgb, flag, a_g, amax_g, nfl_g);
    k_main<<<dim3(8, 96), 256, 0, stream>>>(qb, kb, vT, a_g, amax_g, h_buf, rs_buf);
    k_finish<<<4096, 256, 0, stream>>>(h_buf, rs_buf, nfl_g, ow, flag, d_out);
}

// Round 16
// 246.217 us; speedup vs baseline: 1.1822x; 1.1822x over previous
//
#include <hip/hip_runtime.h>
#include <hip/hip_bf16.h>

#define SEQ 2048
#define DMODEL 2048
#define NHEAD 8
#define DHEAD 256

typedef _Float16 v8h __attribute__((ext_vector_type(8)));
typedef unsigned short v8u __attribute__((ext_vector_type(8)));
typedef float v4f __attribute__((ext_vector_type(4)));

__device__ __forceinline__ float b2f(unsigned short s) {
    return __uint_as_float(((unsigned)s) << 16);
}
__device__ __forceinline__ unsigned short f2b(float f) {
    unsigned u = __float_as_uint(f);
    u += 0x7fffu + ((u >> 16) & 1u);   // RNE
    return (unsigned short)(u >> 16);
}
__device__ __forceinline__ unsigned short f2h(float f) {
    _Float16 h = (_Float16)f;
    return __builtin_bit_cast(unsigned short, h);
}
__device__ __forceinline__ float h2f(unsigned short s) {
    return (float)__builtin_bit_cast(_Float16, s);
}

// --------------------------------------------------------------- fused pre
// Gates made independent of cvt (reads RAW q/k/v, round-0 proven) so both
// roles share one dispatch and overlap:
//   [0,512):     gates (long, VALU/L1-bound; scheduled first)
//   [512,1536):  q,k -> fp16 (streaming cvt)
//   [1536,2560): v -> vT[h][d][s] fp16 (LDS 64x64 tile transpose)
__global__ __launch_bounds__(256) void k_pre(const void* q, const void* k, const void* v,
                                             const void* igk, const void* fgk,
                                             int* flag,
                                             unsigned short* qb, unsigned short* kb,
                                             unsigned short* vT,
                                             float* ipre, float* fpre) {
    __shared__ unsigned short tile[64][72];
    __shared__ float x_lds[32][68];
    __shared__ int cnt;
    const int tid = threadIdx.x;
    const int b = blockIdx.x;

    // local dtype detect (deterministic, L2-hit broadcast; measured free)
    if (tid == 0) cnt = 0;
    __syncthreads();
    {
        const unsigned short* qp = (const unsigned short*)q;
        int wild = 0;
        for (int i = tid; i < 2048; i += 256) {
            float x = b2f(qp[i]);
            float ax = fabsf(x);
            if (!(ax <= 100.0f) || (x != 0.0f && ax < 1e-6f)) wild++;
        }
        atomicAdd(&cnt, wild);
    }
    __syncthreads();
    const int bf = (cnt < 256) ? 1 : 0;
    if (b == 0 && tid == 0) *flag = bf;

    if (b < 512) {
        // ---------------- gates (round-0 structure, raw inputs, broadcast weights)
        const int s0 = (b & 63) * 32;
        const int c  = b >> 6;             // 0..7
        const int sl = tid >> 3, hh = tid & 7;
        const int rr = tid >> 3, j0 = (tid & 7) * 8;
        float accI = 0.f, accF = 0.f;
        const unsigned short* ik16 = (const unsigned short*)igk;
        const unsigned short* fk16 = (const unsigned short*)fgk;
        const float* ik32 = (const float*)igk;
        const float* fk32 = (const float*)fgk;

        for (int wd = 0; wd < 12; ++wd) {
            const int gd0 = c * 768 + wd * 64;
            const void* src; int off;
            if (gd0 < 2048)      { src = q; off = gd0; }
            else if (gd0 < 4096) { src = k; off = gd0 - 2048; }
            else                 { src = v; off = gd0 - 4096; }
            __syncthreads();    // prior chunk fully consumed
            {
                const size_t base = (size_t)(s0 + rr) * DMODEL + off + j0;
                if (bf) {
                    const unsigned short* sp = (const unsigned short*)src;
                    v8u a = *(const v8u*)(sp + base);
#pragma unroll
                    for (int j = 0; j < 8; j++) x_lds[rr][j0 + j] = b2f(a[j]);
                } else {
                    const float* sp = (const float*)src;
                    v4f a0 = *(const v4f*)(sp + base);
                    v4f a1 = *(const v4f*)(sp + base + 4);
#pragma unroll
                    for (int j = 0; j < 4; j++) { x_lds[rr][j0 + j] = a0[j]; x_lds[rr][j0 + 4 + j] = a1[j]; }
                }
            }
            __syncthreads();
            if (bf) {
#pragma unroll 8
                for (int j = 0; j < 64; j++) {
                    float x = x_lds[sl][j];
                    int wi = (gd0 + j) * NHEAD + hh;
                    accI += x * b2f(ik16[wi]);
                    accF += x * b2f(fk16[wi]);
                }
            } else {
#pragma unroll 8
                for (int j = 0; j < 64; j++) {
                    float x = x_lds[sl][j];
                    int wi = (gd0 + j) * NHEAD + hh;
                    accI += x * ik32[wi];
                    accF += x * fk32[wi];
                }
            }
        }
        atomicAdd(&ipre[hh * SEQ + s0 + sl], accI);
        atomicAdd(&fpre[hh * SEQ + s0 + sl], accF);
    } else if (b < 1536) {
        // ---------------- q,k -> fp16 (16 elems per thread per tensor)
        const int b2 = b - 512;
        size_t i0 = ((size_t)b2 * 256 + tid) * 16;
        if (bf) {
            const unsigned short* qp = (const unsigned short*)q;
            const unsigned short* kp = (const unsigned short*)k;
#pragma unroll
            for (int hlf = 0; hlf < 2; hlf++) {
                v8u uq = *(const v8u*)(qp + i0 + hlf * 8);
                v8u uk = *(const v8u*)(kp + i0 + hlf * 8);
                v8u oq, ok;
#pragma unroll
                for (int j = 0; j < 8; j++) { oq[j] = f2h(b2f(uq[j])); ok[j] = f2h(b2f(uk[j])); }
                *(v8u*)(qb + i0 + hlf * 8) = oq;
                *(v8u*)(kb + i0 + hlf * 8) = ok;
            }
        } else {
            const float* qf = (const float*)q;
            const float* kf = (const float*)k;
#pragma unroll
            for (int hlf = 0; hlf < 2; hlf++) {
                v4f q0 = *(const v4f*)(qf + i0 + hlf * 8);
                v4f q1 = *(const v4f*)(qf + i0 + hlf * 8 + 4);
                v4f k0 = *(const v4f*)(kf + i0 + hlf * 8);
                v4f k1 = *(const v4f*)(kf + i0 + hlf * 8 + 4);
                v8u oq, ok;
#pragma unroll
                for (int j = 0; j < 4; j++) {
                    oq[j] = f2h(q0[j]); oq[4 + j] = f2h(q1[j]);
                    ok[j] = f2h(k0[j]); ok[4 + j] = f2h(k1[j]);
                }
                *(v8u*)(qb + i0 + hlf * 8) = oq;
                *(v8u*)(kb + i0 + hlf * 8) = ok;
            }
        }
    } else {
        // ---------------- v -> vT (64x64 tile transpose)
        const int b2 = b - 1536;
        int s0 = (b2 & 31) * 64, d0 = (b2 >> 5) * 64;
        int r = tid >> 2, c0 = (tid & 3) * 16;
        size_t base = (size_t)(s0 + r) * DMODEL + d0 + c0;
        if (bf) {
            const unsigned short* vp = (const unsigned short*)v;
            v8u a = *(const v8u*)(vp + base);
            v8u bb = *(const v8u*)(vp + base + 8);
#pragma unroll
            for (int j = 0; j < 8; j++) { tile[r][c0 + j] = f2h(b2f(a[j])); tile[r][c0 + 8 + j] = f2h(b2f(bb[j])); }
        } else {
            const float* vp = (const float*)v;
            v4f a0 = *(const v4f*)(vp + base);
            v4f a1 = *(const v4f*)(vp + base + 4);
            v4f a2 = *(const v4f*)(vp + base + 8);
            v4f a3 = *(const v4f*)(vp + base + 12);
#pragma unroll
            for (int j = 0; j < 4; j++) {
                tile[r][c0 + j] = f2h(a0[j]);      tile[r][c0 + 4 + j] = f2h(a1[j]);
                tile[r][c0 + 8 + j] = f2h(a2[j]);  tile[r][c0 + 12 + j] = f2h(a3[j]);
            }
        }
        __syncthreads();
        int dr = tid >> 2, sc0 = (tid & 3) * 16;
        v8u o0, o1;
#pragma unroll
        for (int j = 0; j < 8; j++) { o0[j] = tile[sc0 + j][dr]; o1[j] = tile[sc0 + 8 + j][dr]; }
        int head = d0 >> 8;
        int dh = (d0 & 255) + dr;
        size_t ob = ((size_t)head * DHEAD + dh) * SEQ + s0 + sc0;
        *(v8u*)(vT + ob) = o0;
        *(v8u*)(vT + ob + 8) = o1;
    }
}

// ---------------- per-head scans (round-10 verbatim)
__global__ __launch_bounds__(256) void k_scan(const float* ipre, const float* fpre,
                                              const void* ib_, const void* fb_,
                                              const int* flag,
                                              float* a_g, float* amax_g, float* nfl_g) {
    __shared__ float wtot[4], wmax[4];
    int bf = *(volatile const int*)flag;
    int h = blockIdx.x, tid = threadIdx.x;
    int lane = tid & 63, wv = tid >> 6;
    float ib = bf ? b2f(((const unsigned short*)ib_)[h]) : ((const float*)ib_)[h];
    float fb = bf ? b2f(((const unsigned short*)fb_)[h]) : ((const float*)fb_)[h];
    int s0 = tid * 8;
    float lf[8], ip[8];
#pragma unroll
    for (int j = 0; j < 8; j++) {
        float fp = fpre[h * SEQ + s0 + j] + fb;
        lf[j] = fminf(fp, 0.0f) - log1pf(__expf(-fabsf(fp)));
        ip[j] = ipre[h * SEQ + s0 + j] + ib;
    }
    float cs[8]; float t = 0.f;
#pragma unroll
    for (int j = 0; j < 8; j++) { t += lf[j]; cs[j] = t; }
    float incl = t;
#pragma unroll
    for (int o = 1; o < 64; o <<= 1) {
        float n = __shfl_up(incl, o, 64);
        if (lane >= o) incl += n;
    }
    if (lane == 63) wtot[wv] = incl;
    __syncthreads();
    float wpre = 0.f;
#pragma unroll
    for (int i2 = 0; i2 < 4; i2++) if (i2 < wv) wpre += wtot[i2];
    float excl = wpre + incl - t;
    float cum[8], av[8];
#pragma unroll
    for (int j = 0; j < 8; j++) { cum[j] = excl + cs[j]; av[j] = ip[j] - cum[j]; }
    float mx = av[0];
#pragma unroll
    for (int j = 1; j < 8; j++) mx = fmaxf(mx, av[j]);
    float mincl = mx;
#pragma unroll
    for (int o = 1; o < 64; o <<= 1) {
        float n = __shfl_up(mincl, o, 64);
        if (lane >= o) mincl = fmaxf(mincl, n);
    }
    if (lane == 63) wmax[wv] = mincl;
    __syncthreads();
    float wpm = -3.0e38f;
#pragma unroll
    for (int i2 = 0; i2 < 4; i2++) if (i2 < wv) wpm = fmaxf(wpm, wmax[i2]);
    float up = __shfl_up(mincl, 1, 64);
    float run = fmaxf(wpm, (lane > 0) ? up : -3.0e38f);
#pragma unroll
    for (int j = 0; j < 8; j++) {
        run = fmaxf(run, av[j]);
        int s = s0 + j;
        a_g[h * SEQ + s]    = av[j];
        amax_g[h * SEQ + s] = run;
        float m = cum[j] + run;
        nfl_g[h * SEQ + s]  = __expf(fminf(fmaxf(-m, -60.f), 60.f));
    }
}

// --------------------------------------------------------------- main kernel
// ROUND-10 EXACT (measured 82.7-83.3 us): Q in per-wave registers, K/V LDS
// staging with async-split (load early, ds_write late), P hi/lo, w3 MFMA
// normalizer, equal-work quota blocks, atomic flush into h_buf/rs_buf.
__global__ __launch_bounds__(256, 3) void k_main(const unsigned short* __restrict__ qb,
                                                 const unsigned short* __restrict__ kb,
                                                 const unsigned short* __restrict__ vT,
                                                 const float* __restrict__ a_g,
                                                 const float* __restrict__ amax_g,
                                                 float* __restrict__ h_buf,
                                                 float* __restrict__ rs_buf) {
    __shared__ __align__(16) unsigned short k_lds[32][264];
    __shared__ __align__(16) unsigned short vT_lds[272][40];   // rows 256..271: ones/zeros
    __shared__ __align__(16) unsigned short P_lds[32][40];
    __shared__ __align__(16) unsigned short Plo_lds[32][40];
    __shared__ float a_s[32], amax_t[32];

    const int h   = blockIdx.x;
    const int y   = blockIdx.y;        // quota index within head, 0..95
    const int tid = threadIdx.x;
    const int lane = tid & 63;
    const int w   = tid >> 6;          // wave 0..3
    const int l15 = lane & 15;
    const int qd  = (lane >> 4) & 3;   // quad
    const int hd0 = h * DHEAD;

    // ---- quota: units [u, u_end) of this head's flattened triangle
    int u         = (y * 2080) / 96;
    int remaining = ((y + 1) * 2080) / 96 - u;
    int tile = (int)((sqrtf(8.0f * (float)u + 1.0f) - 1.0f) * 0.5f);
    while ((tile + 1) * (tile + 2) / 2 <= u) ++tile;
    while (tile * (tile + 1) / 2 > u) --tile;
    int js = u - tile * (tile + 1) / 2;
    bool needQ = true;

    // ones/zeros rows for the normalizer trick
    for (int i = tid; i < 16 * 40; i += 256) {
        int r2 = i / 40, c2 = i % 40;
        vT_lds[256 + r2][c2] = (r2 == 0 && c2 < 32) ? (unsigned short)0x3C00 : (unsigned short)0;
    }

    const v4f vzero = {0.f, 0.f, 0.f, 0.f};
    v4f acc[2][4];
    v4f accN[2];
#pragma unroll
    for (int m = 0; m < 2; m++) {
        accN[m] = vzero;
#pragma unroll
        for (int n = 0; n < 4; n++) acc[m][n] = vzero;
    }

    const int mw = w >> 1, nw = w & 1;
    const int krow = tid >> 3, kc0 = (tid & 7) * 32;

    // Q fragment in registers: this wave's 16 rows x its qd-column slices
    v8u qr[8];

    // staging registers (async-split: load early, ds_write late)
    v8u kr0, kr1, kr2, kr3, vr0, vr1, vr2, vr3;
    float areg = 0.f;
    {   // prefetch first unit
        const int s0 = js * 32;
        const unsigned short* ks = kb + (size_t)(s0 + krow) * DMODEL + hd0 + kc0;
        kr0 = *(const v8u*)(ks);      kr1 = *(const v8u*)(ks + 8);
        kr2 = *(const v8u*)(ks + 16); kr3 = *(const v8u*)(ks + 24);
        const unsigned short* vs = vT + (size_t)(hd0 + tid) * SEQ + s0;
        vr0 = *(const v8u*)(vs);      vr1 = *(const v8u*)(vs + 8);
        vr2 = *(const v8u*)(vs + 16); vr3 = *(const v8u*)(vs + 24);
        if (tid < 32) areg = a_g[h * SEQ + s0 + tid];
    }

    for (;;) {
        const int t0 = tile * 32;
        __syncthreads();   // previous unit consumed k/vT/P
        if (needQ) {       // new tile: Q fragment -> registers + per-row stabilizer
            const unsigned short* src = qb + (size_t)(t0 + mw * 16 + l15) * DMODEL + hd0 + qd * 8;
#pragma unroll
            for (int i = 0; i < 8; i++)
                qr[i] = *(const v8u*)(src + i * 32);
            if (tid < 32) amax_t[tid] = amax_g[h * SEQ + t0 + tid];
            needQ = false;
        }
        *(v8u*)&k_lds[krow][kc0]      = kr0;
        *(v8u*)&k_lds[krow][kc0 + 8]  = kr1;
        *(v8u*)&k_lds[krow][kc0 + 16] = kr2;
        *(v8u*)&k_lds[krow][kc0 + 24] = kr3;
        *(v8u*)&vT_lds[tid][0]  = vr0;
        *(v8u*)&vT_lds[tid][8]  = vr1;
        *(v8u*)&vT_lds[tid][16] = vr2;
        *(v8u*)&vT_lds[tid][24] = vr3;
        if (tid < 32) a_s[tid] = areg;
        __syncthreads();

        // QK^T: each wave computes one 16x16 tile of P (mw,nw); A from registers
        v4f c = vzero;
#pragma unroll
        for (int i = 0; i < 8; i++) {
            v8h a = __builtin_bit_cast(v8h, qr[i]);
            v8h b = *(const v8h*)&k_lds[nw * 16 + l15][i * 32 + qd * 8];
            c = __builtin_amdgcn_mfma_f32_16x16x32_f16(a, b, c, 0, 0, 0);
        }
        // decay weights + causal mask; write P as fp16 hi + lo residual
        {
            const bool diag = (js == tile);
            const int col = nw * 16 + l15;
            const float av = a_s[col];
#pragma unroll
            for (int r = 0; r < 4; r++) {
                int row = mw * 16 + qd * 4 + r;
                float arg = fminf(av - amax_t[row], 0.0f);
                float val = c[r] * 0.0625f * __expf(arg);   // 1/sqrt(256) folded here
                if (diag && col > row) val = 0.0f;
                unsigned short hi = f2h(val);
                float lo = val - h2f(hi);
                P_lds[row][col]   = hi;
                Plo_lds[row][col] = f2h(lo);
            }
        }
        __syncthreads();

        // prefetch NEXT unit now; HBM/L2 latency hides under the PV phase below
        int ntile = tile, njs = js + 1; bool nq = false;
        if (njs > tile) { ntile = tile + 1; njs = 0; nq = true; }
        if (remaining > 1) {
            const int s0 = njs * 32;
            const unsigned short* ks = kb + (size_t)(s0 + krow) * DMODEL + hd0 + kc0;
            kr0 = *(const v8u*)(ks);      kr1 = *(const v8u*)(ks + 8);
            kr2 = *(const v8u*)(ks + 16); kr3 = *(const v8u*)(ks + 24);
            const unsigned short* vs = vT + (size_t)(hd0 + tid) * SEQ + s0;
            vr0 = *(const v8u*)(vs);      vr1 = *(const v8u*)(vs + 8);
            vr2 = *(const v8u*)(vs + 16); vr3 = *(const v8u*)(vs + 24);
            if (tid < 32) areg = a_g[h * SEQ + s0 + tid];
        }

        // P @ V (hi + lo): wave w owns output cols [w*64, w*64+64)
        v8h aH0 = *(const v8h*)&P_lds[l15][qd * 8];
        v8h aH1 = *(const v8h*)&P_lds[16 + l15][qd * 8];
        v8h aL0 = *(const v8h*)&Plo_lds[l15][qd * 8];
        v8h aL1 = *(const v8h*)&Plo_lds[16 + l15][qd * 8];
#pragma unroll
        for (int nn = 0; nn < 4; nn++) {
            v8h bV = *(const v8h*)&vT_lds[w * 64 + nn * 16 + l15][qd * 8];
            acc[0][nn] = __builtin_amdgcn_mfma_f32_16x16x32_f16(aH0, bV, acc[0][nn], 0, 0, 0);
            acc[0][nn] = __builtin_amdgcn_mfma_f32_16x16x32_f16(aL0, bV, acc[0][nn], 0, 0, 0);
            acc[1][nn] = __builtin_amdgcn_mfma_f32_16x16x32_f16(aH1, bV, acc[1][nn], 0, 0, 0);
            acc[1][nn] = __builtin_amdgcn_mfma_f32_16x16x32_f16(aL1, bV, acc[1][nn], 0, 0, 0);
        }
        if (w == 3) {   // ones-column trick: row normalizer (hi+lo)
            v8h bN = *(const v8h*)&vT_lds[256 + l15][qd * 8];
            accN[0] = __builtin_amdgcn_mfma_f32_16x16x32_f16(aH0, bN, accN[0], 0, 0, 0);
            accN[0] = __builtin_amdgcn_mfma_f32_16x16x32_f16(aL0, bN, accN[0], 0, 0, 0);
            accN[1] = __builtin_amdgcn_mfma_f32_16x16x32_f16(aH1, bN, accN[1], 0, 0, 0);
            accN[1] = __builtin_amdgcn_mfma_f32_16x16x32_f16(aL1, bN, accN[1], 0, 0, 0);
        }

        // flush at tile end or quota end (raw partials; fire-and-forget atomics)
        if (js == tile || remaining == 1) {
#pragma unroll
            for (int m = 0; m < 2; m++)
#pragma unroll
                for (int r = 0; r < 4; r++) {
                    int row = t0 + m * 16 + qd * 4 + r;
#pragma unroll
                    for (int nn = 0; nn < 4; nn++) {
                        int col = hd0 + w * 64 + nn * 16 + l15;
                        atomicAdd(&h_buf[(size_t)row * DMODEL + col], acc[m][nn][r]);
                        acc[m][nn][r] = 0.f;
                    }
                    if (w == 3 && l15 == 0)
                        atomicAdd(&rs_buf[h * SEQ + row], accN[m][r]);
                    accN[m][r] = 0.f;
                }
        }
        if (--remaining == 0) break;
        tile = ntile; js = njs; needQ = nq;
    }
}

// ------------------------------------- finish: normalizer scale + per-head LN
// (round-10 verbatim)
__global__ __launch_bounds__(256) void k_finish(const float* __restrict__ h_buf,
                                                const float* __restrict__ rs_buf,
                                                const float* __restrict__ nfl_g,
                                                const void* __restrict__ ow,
                                                const int* flag, void* out) {
    const int wv = threadIdx.x >> 6, lane = threadIdx.x & 63;
    const int rid = blockIdx.x * 4 + wv;       // 0..16383
    const int s = rid >> 3, h = rid & 7;
    const int bf = *(volatile const int*)flag;
    float rs  = rs_buf[h * SEQ + s];
    float nfl = nfl_g[h * SEQ + s];
    float sc  = 1.0f / (fmaxf(fabsf(rs), nfl) + 1e-6f);
    size_t base = (size_t)s * DMODEL + h * DHEAD + lane * 4;
    v4f hv = *(const v4f*)(h_buf + base);
#pragma unroll
    for (int j = 0; j < 4; j++) hv[j] *= sc;
    float sm = hv[0] + hv[1] + hv[2] + hv[3];
    float sq = hv[0] * hv[0] + hv[1] * hv[1] + hv[2] * hv[2] + hv[3] * hv[3];
#pragma unroll
    for (int m = 1; m < 64; m <<= 1) {
        sm += __shfl_xor(sm, m, 64);
        sq += __shfl_xor(sq, m, 64);
    }
    float mean = sm * (1.0f / 256.0f);
    float var  = fmaxf(sq * (1.0f / 256.0f) - mean * mean, 0.0f);
    float rstd = rsqrtf(var + 1e-6f);
    int gi = h * DHEAD + lane * 4;
    float gv[4];
    if (bf) {
        const unsigned short* gp = (const unsigned short*)ow;
#pragma unroll
        for (int j = 0; j < 4; j++) gv[j] = b2f(gp[gi + j]);
    } else {
        const float* gp = (const float*)ow;
#pragma unroll
        for (int j = 0; j < 4; j++) gv[j] = gp[gi + j];
    }
    if (bf) {
        unsigned short* o = (unsigned short*)out + base;
#pragma unroll
        for (int j = 0; j < 4; j++) o[j] = f2b((hv[j] - mean) * rstd * gv[j]);
    } else {
        float* o = (float*)out + base;
#pragma unroll
        for (int j = 0; j < 4; j++) o[j] = (hv[j] - mean) * rstd * gv[j];
    }
}

// ---------------------------------------------------------------------- host
extern "C" void kernel_launch(void* const* d_in, const int* in_sizes, int n_in,
                              void* d_out, int out_size, void* d_ws, size_t ws_size,
                              hipStream_t stream) {
    const void* q   = d_in[0];
    const void* k   = d_in[1];
    const void* v   = d_in[2];
    const void* igk = d_in[3];
    const void* igb = d_in[4];
    const void* fgk = d_in[5];
    const void* fgb = d_in[6];
    const void* ow  = d_in[7];

    char* ws = (char*)d_ws;
    int*   flag   = (int*)(ws + 0);
    // zeroed region (contiguous, one memset): ipre | fpre | rs_buf | h_buf
    float* ipre   = (float*)(ws + 1024);
    float* fpre   = ipre + NHEAD * SEQ;
    float* rs_buf = fpre + NHEAD * SEQ;
    float* h_buf  = rs_buf + NHEAD * SEQ;
    float* a_g    = h_buf + (size_t)SEQ * DMODEL;
    float* amax_g = a_g + NHEAD * SEQ;
    float* nfl_g  = amax_g + NHEAD * SEQ;
    unsigned short* qb = (unsigned short*)(nfl_g + NHEAD * SEQ);
    unsigned short* kb = qb + (size_t)SEQ * DMODEL;
    unsigned short* vT = kb + (size_t)SEQ * DMODEL;

    size_t zbytes = (size_t)(3 * NHEAD * SEQ) * 4 + (size_t)SEQ * DMODEL * 4;
    hipMemsetAsync(ipre, 0, zbytes, stream);
    k_pre<<<2560, 256, 0, stream>>>(q, k, v, igk, fgk, flag, qb, kb, vT, ipre, fpre);
    k_scan<<<8, 256, 0, stream>>>(ipre, fpre, igb, fgb, flag, a_g, amax_g, nfl_g);
    k_main<<<dim3(8, 96), 256, 0, stream>>>(qb, kb, vT, a_g, amax_g, h_buf, rs_buf);
    k_finish<<<4096, 256, 0, stream>>>(h_buf, rs_buf, nfl_g, ow, flag, d_out);
}

// Round 17
// 242.577 us; speedup vs baseline: 1.2000x; 1.0150x over previous
//
#include <hip/hip_runtime.h>
#include <hip/hip_bf16.h>

#define SEQ 2048
#define DMODEL 2048
#define NHEAD 8
#define DHEAD 256

typedef _Float16 v8h __attribute__((ext_vector_type(8)));
typedef unsigned short v8u __attribute__((ext_vector_type(8)));
typedef float v4f __attribute__((ext_vector_type(4)));

__device__ __forceinline__ float b2f(unsigned short s) {
    return __uint_as_float(((unsigned)s) << 16);
}
__device__ __forceinline__ unsigned short f2b(float f) {
    unsigned u = __float_as_uint(f);
    u += 0x7fffu + ((u >> 16) & 1u);   // RNE
    return (unsigned short)(u >> 16);
}
__device__ __forceinline__ unsigned short f2h(float f) {
    _Float16 h = (_Float16)f;
    return __builtin_bit_cast(unsigned short, h);
}
__device__ __forceinline__ float h2f(unsigned short s) {
    return (float)__builtin_bit_cast(_Float16, s);
}

// --------------------------------------------------------------- fused pre
// Four independent roles in one dispatch (no memset node needed):
//   [0,512):     gates (long, VALU/L1-bound; scheduled first); DETERMINISTIC
//                partial stores iparts[(c*8+hh)*SEQ+s] -- no atomics, no
//                zeroed buffer (partial-sum pattern verified rounds 2/6)
//   [512,1536):  q,k -> fp16 (streaming cvt)
//   [1536,2560): v -> vT[h][d][s] fp16 (LDS 64x64 tile transpose)
//   [2560,3072): zero rs_buf|h_buf (16.8 MB, pure BW; ordered before k_main)
__global__ __launch_bounds__(256) void k_pre(const void* q, const void* k, const void* v,
                                             const void* igk, const void* fgk,
                                             int* flag,
                                             unsigned short* qb, unsigned short* kb,
                                             unsigned short* vT,
                                             float* iparts, float* fparts,
                                             float* zbase) {
    __shared__ unsigned short tile[64][72];
    __shared__ float x_lds[32][68];
    __shared__ int cnt;
    const int tid = threadIdx.x;
    const int b = blockIdx.x;

    // local dtype detect (deterministic, L2-hit broadcast; measured free)
    if (tid == 0) cnt = 0;
    __syncthreads();
    {
        const unsigned short* qp = (const unsigned short*)q;
        int wild = 0;
        for (int i = tid; i < 2048; i += 256) {
            float x = b2f(qp[i]);
            float ax = fabsf(x);
            if (!(ax <= 100.0f) || (x != 0.0f && ax < 1e-6f)) wild++;
        }
        atomicAdd(&cnt, wild);
    }
    __syncthreads();
    const int bf = (cnt < 256) ? 1 : 0;
    if (b == 0 && tid == 0) *flag = bf;

    if (b < 512) {
        // ---------------- gates (round-0 structure, raw inputs, broadcast weights)
        const int s0 = (b & 63) * 32;
        const int c  = b >> 6;             // 0..7
        const int sl = tid >> 3, hh = tid & 7;
        const int rr = tid >> 3, j0 = (tid & 7) * 8;
        float accI = 0.f, accF = 0.f;
        const unsigned short* ik16 = (const unsigned short*)igk;
        const unsigned short* fk16 = (const unsigned short*)fgk;
        const float* ik32 = (const float*)igk;
        const float* fk32 = (const float*)fgk;

        for (int wd = 0; wd < 12; ++wd) {
            const int gd0 = c * 768 + wd * 64;
            const void* src; int off;
            if (gd0 < 2048)      { src = q; off = gd0; }
            else if (gd0 < 4096) { src = k; off = gd0 - 2048; }
            else                 { src = v; off = gd0 - 4096; }
            __syncthreads();    // prior chunk fully consumed
            {
                const size_t base = (size_t)(s0 + rr) * DMODEL + off + j0;
                if (bf) {
                    const unsigned short* sp = (const unsigned short*)src;
                    v8u a = *(const v8u*)(sp + base);
#pragma unroll
                    for (int j = 0; j < 8; j++) x_lds[rr][j0 + j] = b2f(a[j]);
                } else {
                    const float* sp = (const float*)src;
                    v4f a0 = *(const v4f*)(sp + base);
                    v4f a1 = *(const v4f*)(sp + base + 4);
#pragma unroll
                    for (int j = 0; j < 4; j++) { x_lds[rr][j0 + j] = a0[j]; x_lds[rr][j0 + 4 + j] = a1[j]; }
                }
            }
            __syncthreads();
            if (bf) {
#pragma unroll 8
                for (int j = 0; j < 64; j++) {
                    float x = x_lds[sl][j];
                    int wi = (gd0 + j) * NHEAD + hh;
                    accI += x * b2f(ik16[wi]);
                    accF += x * b2f(fk16[wi]);
                }
            } else {
#pragma unroll 8
                for (int j = 0; j < 64; j++) {
                    float x = x_lds[sl][j];
                    int wi = (gd0 + j) * NHEAD + hh;
                    accI += x * ik32[wi];
                    accF += x * fk32[wi];
                }
            }
        }
        iparts[(size_t)(c * NHEAD + hh) * SEQ + s0 + sl] = accI;
        fparts[(size_t)(c * NHEAD + hh) * SEQ + s0 + sl] = accF;
    } else if (b < 1536) {
        // ---------------- q,k -> fp16 (16 elems per thread per tensor)
        const int b2 = b - 512;
        size_t i0 = ((size_t)b2 * 256 + tid) * 16;
        if (bf) {
            const unsigned short* qp = (const unsigned short*)q;
            const unsigned short* kp = (const unsigned short*)k;
#pragma unroll
            for (int hlf = 0; hlf < 2; hlf++) {
                v8u uq = *(const v8u*)(qp + i0 + hlf * 8);
                v8u uk = *(const v8u*)(kp + i0 + hlf * 8);
                v8u oq, ok;
#pragma unroll
                for (int j = 0; j < 8; j++) { oq[j] = f2h(b2f(uq[j])); ok[j] = f2h(b2f(uk[j])); }
                *(v8u*)(qb + i0 + hlf * 8) = oq;
                *(v8u*)(kb + i0 + hlf * 8) = ok;
            }
        } else {
            const float* qf = (const float*)q;
            const float* kf = (const float*)k;
#pragma unroll
            for (int hlf = 0; hlf < 2; hlf++) {
                v4f q0 = *(const v4f*)(qf + i0 + hlf * 8);
                v4f q1 = *(const v4f*)(qf + i0 + hlf * 8 + 4);
                v4f k0 = *(const v4f*)(kf + i0 + hlf * 8);
                v4f k1 = *(const v4f*)(kf + i0 + hlf * 8 + 4);
                v8u oq, ok;
#pragma unroll
                for (int j = 0; j < 4; j++) {
                    oq[j] = f2h(q0[j]); oq[4 + j] = f2h(q1[j]);
                    ok[j] = f2h(k0[j]); ok[4 + j] = f2h(k1[j]);
                }
                *(v8u*)(qb + i0 + hlf * 8) = oq;
                *(v8u*)(kb + i0 + hlf * 8) = ok;
            }
        }
    } else if (b < 2560) {
        // ---------------- v -> vT (64x64 tile transpose)
        const int b2 = b - 1536;
        int s0 = (b2 & 31) * 64, d0 = (b2 >> 5) * 64;
        int r = tid >> 2, c0 = (tid & 3) * 16;
        size_t base = (size_t)(s0 + r) * DMODEL + d0 + c0;
        if (bf) {
            const unsigned short* vp = (const unsigned short*)v;
            v8u a = *(const v8u*)(vp + base);
            v8u bb = *(const v8u*)(vp + base + 8);
#pragma unroll
            for (int j = 0; j < 8; j++) { tile[r][c0 + j] = f2h(b2f(a[j])); tile[r][c0 + 8 + j] = f2h(b2f(bb[j])); }
        } else {
            const float* vp = (const float*)v;
            v4f a0 = *(const v4f*)(vp + base);
            v4f a1 = *(const v4f*)(vp + base + 4);
            v4f a2 = *(const v4f*)(vp + base + 8);
            v4f a3 = *(const v4f*)(vp + base + 12);
#pragma unroll
            for (int j = 0; j < 4; j++) {
                tile[r][c0 + j] = f2h(a0[j]);      tile[r][c0 + 4 + j] = f2h(a1[j]);
                tile[r][c0 + 8 + j] = f2h(a2[j]);  tile[r][c0 + 12 + j] = f2h(a3[j]);
            }
        }
        __syncthreads();
        int dr = tid >> 2, sc0 = (tid & 3) * 16;
        v8u o0, o1;
#pragma unroll
        for (int j = 0; j < 8; j++) { o0[j] = tile[sc0 + j][dr]; o1[j] = tile[sc0 + 8 + j][dr]; }
        int head = d0 >> 8;
        int dh = (d0 & 255) + dr;
        size_t ob = ((size_t)head * DHEAD + dh) * SEQ + s0 + sc0;
        *(v8u*)(vT + ob) = o0;
        *(v8u*)(vT + ob + 8) = o1;
    } else {
        // ---------------- zero rs_buf|h_buf (contiguous f32 region)
        const int b2 = b - 2560;           // 0..511
        const v4f vz = {0.f, 0.f, 0.f, 0.f};
        const size_t ztot = (size_t)NHEAD * SEQ + (size_t)SEQ * DMODEL;  // f32 count
        size_t idx = ((size_t)b2 * 256 + tid) * 4;
        const size_t stride = (size_t)512 * 256 * 4;
        for (; idx + 4 <= ztot; idx += stride)
            *(v4f*)(zbase + idx) = vz;
    }
}

// ---------------- per-head scans: cum(log_sigmoid(f)), a = i - cum, prefix-max
// shfl-based scans; sums the 8 deterministic gate partials.
__global__ __launch_bounds__(256) void k_scan(const float* iparts, const float* fparts,
                                              const void* ib_, const void* fb_,
                                              const int* flag,
                                              float* a_g, float* amax_g, float* nfl_g) {
    __shared__ float wtot[4], wmax[4];
    int bf = *(volatile const int*)flag;
    int h = blockIdx.x, tid = threadIdx.x;
    int lane = tid & 63, wv = tid >> 6;
    float ib = bf ? b2f(((const unsigned short*)ib_)[h]) : ((const float*)ib_)[h];
    float fb = bf ? b2f(((const unsigned short*)fb_)[h]) : ((const float*)fb_)[h];
    int s0 = tid * 8;
    float lf[8], ip[8];
#pragma unroll
    for (int j = 0; j < 8; j++) {
        float fp = fb, ipv = ib;
#pragma unroll
        for (int z = 0; z < 8; z++) {
            ipv += iparts[(size_t)(z * NHEAD + h) * SEQ + s0 + j];
            fp  += fparts[(size_t)(z * NHEAD + h) * SEQ + s0 + j];
        }
        lf[j] = fminf(fp, 0.0f) - log1pf(__expf(-fabsf(fp)));
        ip[j] = ipv;
    }
    float cs[8]; float t = 0.f;
#pragma unroll
    for (int j = 0; j < 8; j++) { t += lf[j]; cs[j] = t; }
    // inclusive wave scan (sum)
    float incl = t;
#pragma unroll
    for (int o = 1; o < 64; o <<= 1) {
        float n = __shfl_up(incl, o, 64);
        if (lane >= o) incl += n;
    }
    if (lane == 63) wtot[wv] = incl;
    __syncthreads();
    float wpre = 0.f;
#pragma unroll
    for (int i2 = 0; i2 < 4; i2++) if (i2 < wv) wpre += wtot[i2];
    float excl = wpre + incl - t;
    float cum[8], av[8];
#pragma unroll
    for (int j = 0; j < 8; j++) { cum[j] = excl + cs[j]; av[j] = ip[j] - cum[j]; }
    float mx = av[0];
#pragma unroll
    for (int j = 1; j < 8; j++) mx = fmaxf(mx, av[j]);
    // inclusive wave scan (max)
    float mincl = mx;
#pragma unroll
    for (int o = 1; o < 64; o <<= 1) {
        float n = __shfl_up(mincl, o, 64);
        if (lane >= o) mincl = fmaxf(mincl, n);
    }
    if (lane == 63) wmax[wv] = mincl;
    __syncthreads();
    float wpm = -3.0e38f;
#pragma unroll
    for (int i2 = 0; i2 < 4; i2++) if (i2 < wv) wpm = fmaxf(wpm, wmax[i2]);
    float up = __shfl_up(mincl, 1, 64);
    float run = fmaxf(wpm, (lane > 0) ? up : -3.0e38f);
#pragma unroll
    for (int j = 0; j < 8; j++) {
        run = fmaxf(run, av[j]);
        int s = s0 + j;
        a_g[h * SEQ + s]    = av[j];
        amax_g[h * SEQ + s] = run;
        float m = cum[j] + run;
        nfl_g[h * SEQ + s]  = __expf(fminf(fmaxf(-m, -60.f), 60.f));
    }
}

// --------------------------------------------------------------- main kernel
// ROUND-10/16 EXACT (measured 82.2-83.3 us, four clean runs): Q in per-wave
// registers, K/V LDS staging with async-split (load early, ds_write late),
// P hi/lo, w3 MFMA normalizer, equal-work quota blocks, atomic flush.
__global__ __launch_bounds__(256, 3) void k_main(const unsigned short* __restrict__ qb,
                                                 const unsigned short* __restrict__ kb,
                                                 const unsigned short* __restrict__ vT,
                                                 const float* __restrict__ a_g,
                                                 const float* __restrict__ amax_g,
                                                 float* __restrict__ h_buf,
                                                 float* __restrict__ rs_buf) {
    __shared__ __align__(16) unsigned short k_lds[32][264];
    __shared__ __align__(16) unsigned short vT_lds[272][40];   // rows 256..271: ones/zeros
    __shared__ __align__(16) unsigned short P_lds[32][40];
    __shared__ __align__(16) unsigned short Plo_lds[32][40];
    __shared__ float a_s[32], amax_t[32];

    const int h   = blockIdx.x;
    const int y   = blockIdx.y;        // quota index within head, 0..95
    const int tid = threadIdx.x;
    const int lane = tid & 63;
    const int w   = tid >> 6;          // wave 0..3
    const int l15 = lane & 15;
    const int qd  = (lane >> 4) & 3;   // quad
    const int hd0 = h * DHEAD;

    // ---- quota: units [u, u_end) of this head's flattened triangle
    int u         = (y * 2080) / 96;
    int remaining = ((y + 1) * 2080) / 96 - u;
    int tile = (int)((sqrtf(8.0f * (float)u + 1.0f) - 1.0f) * 0.5f);
    while ((tile + 1) * (tile + 2) / 2 <= u) ++tile;
    while (tile * (tile + 1) / 2 > u) --tile;
    int js = u - tile * (tile + 1) / 2;
    bool needQ = true;

    // ones/zeros rows for the normalizer trick
    for (int i = tid; i < 16 * 40; i += 256) {
        int r2 = i / 40, c2 = i % 40;
        vT_lds[256 + r2][c2] = (r2 == 0 && c2 < 32) ? (unsigned short)0x3C00 : (unsigned short)0;
    }

    const v4f vzero = {0.f, 0.f, 0.f, 0.f};
    v4f acc[2][4];
    v4f accN[2];
#pragma unroll
    for (int m = 0; m < 2; m++) {
        accN[m] = vzero;
#pragma unroll
        for (int n = 0; n < 4; n++) acc[m][n] = vzero;
    }

    const int mw = w >> 1, nw = w & 1;
    const int krow = tid >> 3, kc0 = (tid & 7) * 32;

    // Q fragment in registers: this wave's 16 rows x its qd-column slices
    v8u qr[8];

    // staging registers (async-split: load early, ds_write late)
    v8u kr0, kr1, kr2, kr3, vr0, vr1, vr2, vr3;
    float areg = 0.f;
    {   // prefetch first unit
        const int s0 = js * 32;
        const unsigned short* ks = kb + (size_t)(s0 + krow) * DMODEL + hd0 + kc0;
        kr0 = *(const v8u*)(ks);      kr1 = *(const v8u*)(ks + 8);
        kr2 = *(const v8u*)(ks + 16); kr3 = *(const v8u*)(ks + 24);
        const unsigned short* vs = vT + (size_t)(hd0 + tid) * SEQ + s0;
        vr0 = *(const v8u*)(vs);      vr1 = *(const v8u*)(vs + 8);
        vr2 = *(const v8u*)(vs + 16); vr3 = *(const v8u*)(vs + 24);
        if (tid < 32) areg = a_g[h * SEQ + s0 + tid];
    }

    for (;;) {
        const int t0 = tile * 32;
        __syncthreads();   // previous unit consumed k/vT/P
        if (needQ) {       // new tile: Q fragment -> registers + per-row stabilizer
            const unsigned short* src = qb + (size_t)(t0 + mw * 16 + l15) * DMODEL + hd0 + qd * 8;
#pragma unroll
            for (int i = 0; i < 8; i++)
                qr[i] = *(const v8u*)(src + i * 32);
            if (tid < 32) amax_t[tid] = amax_g[h * SEQ + t0 + tid];
            needQ = false;
        }
        *(v8u*)&k_lds[krow][kc0]      = kr0;
        *(v8u*)&k_lds[krow][kc0 + 8]  = kr1;
        *(v8u*)&k_lds[krow][kc0 + 16] = kr2;
        *(v8u*)&k_lds[krow][kc0 + 24] = kr3;
        *(v8u*)&vT_lds[tid][0]  = vr0;
        *(v8u*)&vT_lds[tid][8]  = vr1;
        *(v8u*)&vT_lds[tid][16] = vr2;
        *(v8u*)&vT_lds[tid][24] = vr3;
        if (tid < 32) a_s[tid] = areg;
        __syncthreads();

        // QK^T: each wave computes one 16x16 tile of P (mw,nw); A from registers
        v4f c = vzero;
#pragma unroll
        for (int i = 0; i < 8; i++) {
            v8h a = __builtin_bit_cast(v8h, qr[i]);
            v8h b = *(const v8h*)&k_lds[nw * 16 + l15][i * 32 + qd * 8];
            c = __builtin_amdgcn_mfma_f32_16x16x32_f16(a, b, c, 0, 0, 0);
        }
        // decay weights + causal mask; write P as fp16 hi + lo residual
        {
            const bool diag = (js == tile);
            const int col = nw * 16 + l15;
            const float av = a_s[col];
#pragma unroll
            for (int r = 0; r < 4; r++) {
                int row = mw * 16 + qd * 4 + r;
                float arg = fminf(av - amax_t[row], 0.0f);
                float val = c[r] * 0.0625f * __expf(arg);   // 1/sqrt(256) folded here
                if (diag && col > row) val = 0.0f;
                unsigned short hi = f2h(val);
                float lo = val - h2f(hi);
                P_lds[row][col]   = hi;
                Plo_lds[row][col] = f2h(lo);
            }
        }
        __syncthreads();

        // prefetch NEXT unit now; HBM/L2 latency hides under the PV phase below
        int ntile = tile, njs = js + 1; bool nq = false;
        if (njs > tile) { ntile = tile + 1; njs = 0; nq = true; }
        if (remaining > 1) {
            const int s0 = njs * 32;
            const unsigned short* ks = kb + (size_t)(s0 + krow) * DMODEL + hd0 + kc0;
            kr0 = *(const v8u*)(ks);      kr1 = *(const v8u*)(ks + 8);
            kr2 = *(const v8u*)(ks + 16); kr3 = *(const v8u*)(ks + 24);
            const unsigned short* vs = vT + (size_t)(hd0 + tid) * SEQ + s0;
            vr0 = *(const v8u*)(vs);      vr1 = *(const v8u*)(vs + 8);
            vr2 = *(const v8u*)(vs + 16); vr3 = *(const v8u*)(vs + 24);
            if (tid < 32) areg = a_g[h * SEQ + s0 + tid];
        }

        // P @ V (hi + lo): wave w owns output cols [w*64, w*64+64)
        v8h aH0 = *(const v8h*)&P_lds[l15][qd * 8];
        v8h aH1 = *(const v8h*)&P_lds[16 + l15][qd * 8];
        v8h aL0 = *(const v8h*)&Plo_lds[l15][qd * 8];
        v8h aL1 = *(const v8h*)&Plo_lds[16 + l15][qd * 8];
#pragma unroll
        for (int nn = 0; nn < 4; nn++) {
            v8h bV = *(const v8h*)&vT_lds[w * 64 + nn * 16 + l15][qd * 8];
            acc[0][nn] = __builtin_amdgcn_mfma_f32_16x16x32_f16(aH0, bV, acc[0][nn], 0, 0, 0);
            acc[0][nn] = __builtin_amdgcn_mfma_f32_16x16x32_f16(aL0, bV, acc[0][nn], 0, 0, 0);
            acc[1][nn] = __builtin_amdgcn_mfma_f32_16x16x32_f16(aH1, bV, acc[1][nn], 0, 0, 0);
            acc[1][nn] = __builtin_amdgcn_mfma_f32_16x16x32_f16(aL1, bV, acc[1][nn], 0, 0, 0);
        }
        if (w == 3) {   // ones-column trick: row normalizer (hi+lo)
            v8h bN = *(const v8h*)&vT_lds[256 + l15][qd * 8];
            accN[0] = __builtin_amdgcn_mfma_f32_16x16x32_f16(aH0, bN, accN[0], 0, 0, 0);
            accN[0] = __builtin_amdgcn_mfma_f32_16x16x32_f16(aL0, bN, accN[0], 0, 0, 0);
            accN[1] = __builtin_amdgcn_mfma_f32_16x16x32_f16(aH1, bN, accN[1], 0, 0, 0);
            accN[1] = __builtin_amdgcn_mfma_f32_16x16x32_f16(aL1, bN, accN[1], 0, 0, 0);
        }

        // flush at tile end or quota end (raw partials; fire-and-forget atomics)
        if (js == tile || remaining == 1) {
#pragma unroll
            for (int m = 0; m < 2; m++)
#pragma unroll
                for (int r = 0; r < 4; r++) {
                    int row = t0 + m * 16 + qd * 4 + r;
#pragma unroll
                    for (int nn = 0; nn < 4; nn++) {
                        int col = hd0 + w * 64 + nn * 16 + l15;
                        atomicAdd(&h_buf[(size_t)row * DMODEL + col], acc[m][nn][r]);
                        acc[m][nn][r] = 0.f;
                    }
                    if (w == 3 && l15 == 0)
                        atomicAdd(&rs_buf[h * SEQ + row], accN[m][r]);
                    accN[m][r] = 0.f;
                }
        }
        if (--remaining == 0) break;
        tile = ntile; js = njs; needQ = nq;
    }
}

// ------------------------------------- finish: normalizer scale + per-head LN
// (round-10/16 verbatim)
__global__ __launch_bounds__(256) void k_finish(const float* __restrict__ h_buf,
                                                const float* __restrict__ rs_buf,
                                                const float* __restrict__ nfl_g,
                                                const void* __restrict__ ow,
                                                const int* flag, void* out) {
    const int wv = threadIdx.x >> 6, lane = threadIdx.x & 63;
    const int rid = blockIdx.x * 4 + wv;       // 0..16383
    const int s = rid >> 3, h = rid & 7;
    const int bf = *(volatile const int*)flag;
    float rs  = rs_buf[h * SEQ + s];
    float nfl = nfl_g[h * SEQ + s];
    float sc  = 1.0f / (fmaxf(fabsf(rs), nfl) + 1e-6f);
    size_t base = (size_t)s * DMODEL + h * DHEAD + lane * 4;
    v4f hv = *(const v4f*)(h_buf + base);
#pragma unroll
    for (int j = 0; j < 4; j++) hv[j] *= sc;
    float sm = hv[0] + hv[1] + hv[2] + hv[3];
    float sq = hv[0] * hv[0] + hv[1] * hv[1] + hv[2] * hv[2] + hv[3] * hv[3];
#pragma unroll
    for (int m = 1; m < 64; m <<= 1) {
        sm += __shfl_xor(sm, m, 64);
        sq += __shfl_xor(sq, m, 64);
    }
    float mean = sm * (1.0f / 256.0f);
    float var  = fmaxf(sq * (1.0f / 256.0f) - mean * mean, 0.0f);
    float rstd = rsqrtf(var + 1e-6f);
    int gi = h * DHEAD + lane * 4;
    float gv[4];
    if (bf) {
        const unsigned short* gp = (const unsigned short*)ow;
#pragma unroll
        for (int j = 0; j < 4; j++) gv[j] = b2f(gp[gi + j]);
    } else {
        const float* gp = (const float*)ow;
#pragma unroll
        for (int j = 0; j < 4; j++) gv[j] = gp[gi + j];
    }
    if (bf) {
        unsigned short* o = (unsigned short*)out + base;
#pragma unroll
        for (int j = 0; j < 4; j++) o[j] = f2b((hv[j] - mean) * rstd * gv[j]);
    } else {
        float* o = (float*)out + base;
#pragma unroll
        for (int j = 0; j < 4; j++) o[j] = (hv[j] - mean) * rstd * gv[j];
    }
}

// ---------------------------------------------------------------------- host
extern "C" void kernel_launch(void* const* d_in, const int* in_sizes, int n_in,
                              void* d_out, int out_size, void* d_ws, size_t ws_size,
                              hipStream_t stream) {
    const void* q   = d_in[0];
    const void* k   = d_in[1];
    const void* v   = d_in[2];
    const void* igk = d_in[3];
    const void* igb = d_in[4];
    const void* fgk = d_in[5];
    const void* fgb = d_in[6];
    const void* ow  = d_in[7];

    char* ws = (char*)d_ws;
    int*   flag   = (int*)(ws + 0);
    float* iparts = (float*)(ws + 1024);                       // 8*8*2048 f32 = 512 KiB
    float* fparts = iparts + 8 * NHEAD * SEQ;
    float* a_g    = fparts + 8 * NHEAD * SEQ;
    float* amax_g = a_g + NHEAD * SEQ;
    float* nfl_g  = amax_g + NHEAD * SEQ;
    // zeroed-by-k_pre region (contiguous): rs_buf | h_buf
    float* rs_buf = nfl_g + NHEAD * SEQ;
    float* h_buf  = rs_buf + NHEAD * SEQ;
    unsigned short* qb = (unsigned short*)(h_buf + (size_t)SEQ * DMODEL);
    unsigned short* kb = qb + (size_t)SEQ * DMODEL;
    unsigned short* vT = kb + (size_t)SEQ * DMODEL;

    // 4 graph nodes, no memset
    k_pre<<<3072, 256, 0, stream>>>(q, k, v, igk, fgk, flag, qb, kb, vT, iparts, fparts, rs_buf);
    k_scan<<<8, 256, 0, stream>>>(iparts, fparts, igb, fgb, flag, a_g, amax_g, nfl_g);
    k_main<<<dim3(8, 96), 256, 0, stream>>>(qb, kb, vT, a_g, amax_g, h_buf, rs_buf);
    k_finish<<<4096, 256, 0, stream>>>(h_buf, rs_buf, nfl_g, ow, flag, d_out);
}

// Round 18
// 228.897 us; speedup vs baseline: 1.2717x; 1.0598x over previous
//
#include <hip/hip_runtime.h>
#include <hip/hip_bf16.h>

#define SEQ 2048
#define DMODEL 2048
#define NHEAD 8
#define DHEAD 256

typedef _Float16 v8h __attribute__((ext_vector_type(8)));
typedef unsigned short v8u __attribute__((ext_vector_type(8)));
typedef float v4f __attribute__((ext_vector_type(4)));

__device__ __forceinline__ float b2f(unsigned short s) {
    return __uint_as_float(((unsigned)s) << 16);
}
__device__ __forceinline__ unsigned short f2b(float f) {
    unsigned u = __float_as_uint(f);
    u += 0x7fffu + ((u >> 16) & 1u);   // RNE
    return (unsigned short)(u >> 16);
}
__device__ __forceinline__ unsigned short f2h(float f) {
    _Float16 h = (_Float16)f;
    return __builtin_bit_cast(unsigned short, h);
}
__device__ __forceinline__ float h2f(unsigned short s) {
    return (float)__builtin_bit_cast(_Float16, s);
}

// --------------------------------------------------------------- fused pre
// Four independent roles in one dispatch (no memset node):
//   [0,1024):    gates, 16 x 384-d chunks (2x parallelism vs round-17);
//                DETERMINISTIC partial stores -- no atomics, no zeroed buffer
//   [1024,2048): q,k -> fp16 (streaming cvt)
//   [2048,3072): v -> vT[h][d][s] fp16 (LDS 64x64 tile transpose)
//   [3072,3584): zero rs_buf|h_buf (16.8 MB, pure BW; ordered before k_main)
__global__ __launch_bounds__(256) void k_pre(const void* q, const void* k, const void* v,
                                             const void* igk, const void* fgk,
                                             int* flag,
                                             unsigned short* qb, unsigned short* kb,
                                             unsigned short* vT,
                                             float* iparts, float* fparts,
                                             float* zbase) {
    __shared__ unsigned short tile[64][72];
    __shared__ float x_lds[32][68];
    __shared__ int cnt;
    const int tid = threadIdx.x;
    const int b = blockIdx.x;

    // local dtype detect (deterministic, L2-hit broadcast; measured free)
    if (tid == 0) cnt = 0;
    __syncthreads();
    {
        const unsigned short* qp = (const unsigned short*)q;
        int wild = 0;
        for (int i = tid; i < 2048; i += 256) {
            float x = b2f(qp[i]);
            float ax = fabsf(x);
            if (!(ax <= 100.0f) || (x != 0.0f && ax < 1e-6f)) wild++;
        }
        atomicAdd(&cnt, wild);
    }
    __syncthreads();
    const int bf = (cnt < 256) ? 1 : 0;
    if (b == 0 && tid == 0) *flag = bf;

    if (b < 1024) {
        // ---------------- gates (broadcast weights; 384-d chunk per block)
        const int s0 = (b & 63) * 32;
        const int c  = b >> 6;             // 0..15
        const int sl = tid >> 3, hh = tid & 7;
        const int rr = tid >> 3, j0 = (tid & 7) * 8;
        float accI = 0.f, accF = 0.f;
        const unsigned short* ik16 = (const unsigned short*)igk;
        const unsigned short* fk16 = (const unsigned short*)fgk;
        const float* ik32 = (const float*)igk;
        const float* fk32 = (const float*)fgk;

        for (int wd = 0; wd < 6; ++wd) {
            const int gd0 = c * 384 + wd * 64;
            const void* src; int off;
            if (gd0 < 2048)      { src = q; off = gd0; }
            else if (gd0 < 4096) { src = k; off = gd0 - 2048; }
            else                 { src = v; off = gd0 - 4096; }
            __syncthreads();    // prior chunk fully consumed
            {
                const size_t base = (size_t)(s0 + rr) * DMODEL + off + j0;
                if (bf) {
                    const unsigned short* sp = (const unsigned short*)src;
                    v8u a = *(const v8u*)(sp + base);
#pragma unroll
                    for (int j = 0; j < 8; j++) x_lds[rr][j0 + j] = b2f(a[j]);
                } else {
                    const float* sp = (const float*)src;
                    v4f a0 = *(const v4f*)(sp + base);
                    v4f a1 = *(const v4f*)(sp + base + 4);
#pragma unroll
                    for (int j = 0; j < 4; j++) { x_lds[rr][j0 + j] = a0[j]; x_lds[rr][j0 + 4 + j] = a1[j]; }
                }
            }
            __syncthreads();
            if (bf) {
#pragma unroll 8
                for (int j = 0; j < 64; j++) {
                    float x = x_lds[sl][j];
                    int wi = (gd0 + j) * NHEAD + hh;
                    accI += x * b2f(ik16[wi]);
                    accF += x * b2f(fk16[wi]);
                }
            } else {
#pragma unroll 8
                for (int j = 0; j < 64; j++) {
                    float x = x_lds[sl][j];
                    int wi = (gd0 + j) * NHEAD + hh;
                    accI += x * ik32[wi];
                    accF += x * fk32[wi];
                }
            }
        }
        iparts[(size_t)(c * NHEAD + hh) * SEQ + s0 + sl] = accI;
        fparts[(size_t)(c * NHEAD + hh) * SEQ + s0 + sl] = accF;
    } else if (b < 2048) {
        // ---------------- q,k -> fp16 (16 elems per thread per tensor)
        const int b2 = b - 1024;
        size_t i0 = ((size_t)b2 * 256 + tid) * 16;
        if (bf) {
            const unsigned short* qp = (const unsigned short*)q;
            const unsigned short* kp = (const unsigned short*)k;
#pragma unroll
            for (int hlf = 0; hlf < 2; hlf++) {
                v8u uq = *(const v8u*)(qp + i0 + hlf * 8);
                v8u uk = *(const v8u*)(kp + i0 + hlf * 8);
                v8u oq, ok;
#pragma unroll
                for (int j = 0; j < 8; j++) { oq[j] = f2h(b2f(uq[j])); ok[j] = f2h(b2f(uk[j])); }
                *(v8u*)(qb + i0 + hlf * 8) = oq;
                *(v8u*)(kb + i0 + hlf * 8) = ok;
            }
        } else {
            const float* qf = (const float*)q;
            const float* kf = (const float*)k;
#pragma unroll
            for (int hlf = 0; hlf < 2; hlf++) {
                v4f q0 = *(const v4f*)(qf + i0 + hlf * 8);
                v4f q1 = *(const v4f*)(qf + i0 + hlf * 8 + 4);
                v4f k0 = *(const v4f*)(kf + i0 + hlf * 8);
                v4f k1 = *(const v4f*)(kf + i0 + hlf * 8 + 4);
                v8u oq, ok;
#pragma unroll
                for (int j = 0; j < 4; j++) {
                    oq[j] = f2h(q0[j]); oq[4 + j] = f2h(q1[j]);
                    ok[j] = f2h(k0[j]); ok[4 + j] = f2h(k1[j]);
                }
                *(v8u*)(qb + i0 + hlf * 8) = oq;
                *(v8u*)(kb + i0 + hlf * 8) = ok;
            }
        }
    } else if (b < 3072) {
        // ---------------- v -> vT (64x64 tile transpose)
        const int b2 = b - 2048;
        int s0 = (b2 & 31) * 64, d0 = (b2 >> 5) * 64;
        int r = tid >> 2, c0 = (tid & 3) * 16;
        size_t base = (size_t)(s0 + r) * DMODEL + d0 + c0;
        if (bf) {
            const unsigned short* vp = (const unsigned short*)v;
            v8u a = *(const v8u*)(vp + base);
            v8u bb = *(const v8u*)(vp + base + 8);
#pragma unroll
            for (int j = 0; j < 8; j++) { tile[r][c0 + j] = f2h(b2f(a[j])); tile[r][c0 + 8 + j] = f2h(b2f(bb[j])); }
        } else {
            const float* vp = (const float*)v;
            v4f a0 = *(const v4f*)(vp + base);
            v4f a1 = *(const v4f*)(vp + base + 4);
            v4f a2 = *(const v4f*)(vp + base + 8);
            v4f a3 = *(const v4f*)(vp + base + 12);
#pragma unroll
            for (int j = 0; j < 4; j++) {
                tile[r][c0 + j] = f2h(a0[j]);      tile[r][c0 + 4 + j] = f2h(a1[j]);
                tile[r][c0 + 8 + j] = f2h(a2[j]);  tile[r][c0 + 12 + j] = f2h(a3[j]);
            }
        }
        __syncthreads();
        int dr = tid >> 2, sc0 = (tid & 3) * 16;
        v8u o0, o1;
#pragma unroll
        for (int j = 0; j < 8; j++) { o0[j] = tile[sc0 + j][dr]; o1[j] = tile[sc0 + 8 + j][dr]; }
        int head = d0 >> 8;
        int dh = (d0 & 255) + dr;
        size_t ob = ((size_t)head * DHEAD + dh) * SEQ + s0 + sc0;
        *(v8u*)(vT + ob) = o0;
        *(v8u*)(vT + ob + 8) = o1;
    } else {
        // ---------------- zero rs_buf|h_buf (contiguous f32 region)
        const int b2 = b - 3072;           // 0..511
        const v4f vz = {0.f, 0.f, 0.f, 0.f};
        const size_t ztot = (size_t)NHEAD * SEQ + (size_t)SEQ * DMODEL;  // f32 count
        size_t idx = ((size_t)b2 * 256 + tid) * 4;
        const size_t stride = (size_t)512 * 256 * 4;
        for (; idx + 4 <= ztot; idx += stride)
            *(v4f*)(zbase + idx) = vz;
    }
}

// ---------------- per-head scans: cum(log_sigmoid(f)), a = i - cum, prefix-max
// shfl-based scans; sums the 16 deterministic gate partials.
__global__ __launch_bounds__(256) void k_scan(const float* iparts, const float* fparts,
                                              const void* ib_, const void* fb_,
                                              const int* flag,
                                              float* a_g, float* amax_g, float* nfl_g) {
    __shared__ float wtot[4], wmax[4];
    int bf = *(volatile const int*)flag;
    int h = blockIdx.x, tid = threadIdx.x;
    int lane = tid & 63, wv = tid >> 6;
    float ib = bf ? b2f(((const unsigned short*)ib_)[h]) : ((const float*)ib_)[h];
    float fb = bf ? b2f(((const unsigned short*)fb_)[h]) : ((const float*)fb_)[h];
    int s0 = tid * 8;
    float lf[8], ip[8];
#pragma unroll
    for (int j = 0; j < 8; j++) {
        float fp = fb, ipv = ib;
#pragma unroll
        for (int z = 0; z < 16; z++) {
            ipv += iparts[(size_t)(z * NHEAD + h) * SEQ + s0 + j];
            fp  += fparts[(size_t)(z * NHEAD + h) * SEQ + s0 + j];
        }
        lf[j] = fminf(fp, 0.0f) - log1pf(__expf(-fabsf(fp)));
        ip[j] = ipv;
    }
    float cs[8]; float t = 0.f;
#pragma unroll
    for (int j = 0; j < 8; j++) { t += lf[j]; cs[j] = t; }
    // inclusive wave scan (sum)
    float incl = t;
#pragma unroll
    for (int o = 1; o < 64; o <<= 1) {
        float n = __shfl_up(incl, o, 64);
        if (lane >= o) incl += n;
    }
    if (lane == 63) wtot[wv] = incl;
    __syncthreads();
    float wpre = 0.f;
#pragma unroll
    for (int i2 = 0; i2 < 4; i2++) if (i2 < wv) wpre += wtot[i2];
    float excl = wpre + incl - t;
    float cum[8], av[8];
#pragma unroll
    for (int j = 0; j < 8; j++) { cum[j] = excl + cs[j]; av[j] = ip[j] - cum[j]; }
    float mx = av[0];
#pragma unroll
    for (int j = 1; j < 8; j++) mx = fmaxf(mx, av[j]);
    // inclusive wave scan (max)
    float mincl = mx;
#pragma unroll
    for (int o = 1; o < 64; o <<= 1) {
        float n = __shfl_up(mincl, o, 64);
        if (lane >= o) mincl = fmaxf(mincl, n);
    }
    if (lane == 63) wmax[wv] = mincl;
    __syncthreads();
    float wpm = -3.0e38f;
#pragma unroll
    for (int i2 = 0; i2 < 4; i2++) if (i2 < wv) wpm = fmaxf(wpm, wmax[i2]);
    float up = __shfl_up(mincl, 1, 64);
    float run = fmaxf(wpm, (lane > 0) ? up : -3.0e38f);
#pragma unroll
    for (int j = 0; j < 8; j++) {
        run = fmaxf(run, av[j]);
        int s = s0 + j;
        a_g[h * SEQ + s]    = av[j];
        amax_g[h * SEQ + s] = run;
        float m = cum[j] + run;
        nfl_g[h * SEQ + s]  = __expf(fminf(fmaxf(-m, -60.f), 60.f));
    }
}

// --------------------------------------------------------------- main kernel
// Round-10/16 structure with the REDUNDANT loop-top barrier removed (2
// barriers/unit). Hazard audit: k_lds last read in QK^T completes before B2
// (same unit, all waves); vT_lds is wave-local (write rows == read rows);
// P_lds/a_s/amax_t writes occur after B1, which syncs all waves past the
// previous unit's PV/decay. No data-flow change otherwise.
__global__ __launch_bounds__(256, 3) void k_main(const unsigned short* __restrict__ qb,
                                                 const unsigned short* __restrict__ kb,
                                                 const unsigned short* __restrict__ vT,
                                                 const float* __restrict__ a_g,
                                                 const float* __restrict__ amax_g,
                                                 float* __restrict__ h_buf,
                                                 float* __restrict__ rs_buf) {
    __shared__ __align__(16) unsigned short k_lds[32][264];
    __shared__ __align__(16) unsigned short vT_lds[272][40];   // rows 256..271: ones/zeros
    __shared__ __align__(16) unsigned short P_lds[32][40];
    __shared__ __align__(16) unsigned short Plo_lds[32][40];
    __shared__ float a_s[32], amax_t[32];

    const int h   = blockIdx.x;
    const int y   = blockIdx.y;        // quota index within head, 0..95
    const int tid = threadIdx.x;
    const int lane = tid & 63;
    const int w   = tid >> 6;          // wave 0..3
    const int l15 = lane & 15;
    const int qd  = (lane >> 4) & 3;   // quad
    const int hd0 = h * DHEAD;

    // ---- quota: units [u, u_end) of this head's flattened triangle
    int u         = (y * 2080) / 96;
    int remaining = ((y + 1) * 2080) / 96 - u;
    int tile = (int)((sqrtf(8.0f * (float)u + 1.0f) - 1.0f) * 0.5f);
    while ((tile + 1) * (tile + 2) / 2 <= u) ++tile;
    while (tile * (tile + 1) / 2 > u) --tile;
    int js = u - tile * (tile + 1) / 2;
    bool needQ = true;

    // ones/zeros rows for the normalizer trick
    for (int i = tid; i < 16 * 40; i += 256) {
        int r2 = i / 40, c2 = i % 40;
        vT_lds[256 + r2][c2] = (r2 == 0 && c2 < 32) ? (unsigned short)0x3C00 : (unsigned short)0;
    }

    const v4f vzero = {0.f, 0.f, 0.f, 0.f};
    v4f acc[2][4];
    v4f accN[2];
#pragma unroll
    for (int m = 0; m < 2; m++) {
        accN[m] = vzero;
#pragma unroll
        for (int n = 0; n < 4; n++) acc[m][n] = vzero;
    }

    const int mw = w >> 1, nw = w & 1;
    const int krow = tid >> 3, kc0 = (tid & 7) * 32;

    // Q fragment in registers: this wave's 16 rows x its qd-column slices
    v8u qr[8];

    // staging registers (async-split: load early, ds_write late)
    v8u kr0, kr1, kr2, kr3, vr0, vr1, vr2, vr3;
    float areg = 0.f;
    {   // prefetch first unit
        const int s0 = js * 32;
        const unsigned short* ks = kb + (size_t)(s0 + krow) * DMODEL + hd0 + kc0;
        kr0 = *(const v8u*)(ks);      kr1 = *(const v8u*)(ks + 8);
        kr2 = *(const v8u*)(ks + 16); kr3 = *(const v8u*)(ks + 24);
        const unsigned short* vs = vT + (size_t)(hd0 + tid) * SEQ + s0;
        vr0 = *(const v8u*)(vs);      vr1 = *(const v8u*)(vs + 8);
        vr2 = *(const v8u*)(vs + 16); vr3 = *(const v8u*)(vs + 24);
        if (tid < 32) areg = a_g[h * SEQ + s0 + tid];
    }

    for (;;) {
        const int t0 = tile * 32;
        // (loop-top barrier removed: B2 of the previous unit already
        //  guarantees k_lds fully read; vT_lds rows are wave-local)
        if (needQ) {       // new tile: Q fragment -> registers + per-row stabilizer
            const unsigned short* src = qb + (size_t)(t0 + mw * 16 + l15) * DMODEL + hd0 + qd * 8;
#pragma unroll
            for (int i = 0; i < 8; i++)
                qr[i] = *(const v8u*)(src + i * 32);
            if (tid < 32) amax_t[tid] = amax_g[h * SEQ + t0 + tid];
            needQ = false;
        }
        *(v8u*)&k_lds[krow][kc0]      = kr0;
        *(v8u*)&k_lds[krow][kc0 + 8]  = kr1;
        *(v8u*)&k_lds[krow][kc0 + 16] = kr2;
        *(v8u*)&k_lds[krow][kc0 + 24] = kr3;
        *(v8u*)&vT_lds[tid][0]  = vr0;
        *(v8u*)&vT_lds[tid][8]  = vr1;
        *(v8u*)&vT_lds[tid][16] = vr2;
        *(v8u*)&vT_lds[tid][24] = vr3;
        if (tid < 32) a_s[tid] = areg;
        __syncthreads();   // B1: staging visible; all waves past prev PV

        // QK^T: each wave computes one 16x16 tile of P (mw,nw); A from registers
        v4f c = vzero;
#pragma unroll
        for (int i = 0; i < 8; i++) {
            v8h a = __builtin_bit_cast(v8h, qr[i]);
            v8h b = *(const v8h*)&k_lds[nw * 16 + l15][i * 32 + qd * 8];
            c = __builtin_amdgcn_mfma_f32_16x16x32_f16(a, b, c, 0, 0, 0);
        }
        // decay weights + causal mask; write P as fp16 hi + lo residual
        {
            const bool diag = (js == tile);
            const int col = nw * 16 + l15;
            const float av = a_s[col];
#pragma unroll
            for (int r = 0; r < 4; r++) {
                int row = mw * 16 + qd * 4 + r;
                float arg = fminf(av - amax_t[row], 0.0f);
                float val = c[r] * 0.0625f * __expf(arg);   // 1/sqrt(256) folded here
                if (diag && col > row) val = 0.0f;
                unsigned short hi = f2h(val);
                float lo = val - h2f(hi);
                P_lds[row][col]   = hi;
                Plo_lds[row][col] = f2h(lo);
            }
        }
        __syncthreads();   // B2: P visible

        // prefetch NEXT unit now; HBM/L2 latency hides under the PV phase below
        int ntile = tile, njs = js + 1; bool nq = false;
        if (njs > tile) { ntile = tile + 1; njs = 0; nq = true; }
        if (remaining > 1) {
            const int s0 = njs * 32;
            const unsigned short* ks = kb + (size_t)(s0 + krow) * DMODEL + hd0 + kc0;
            kr0 = *(const v8u*)(ks);      kr1 = *(const v8u*)(ks + 8);
            kr2 = *(const v8u*)(ks + 16); kr3 = *(const v8u*)(ks + 24);
            const unsigned short* vs = vT + (size_t)(hd0 + tid) * SEQ + s0;
            vr0 = *(const v8u*)(vs);      vr1 = *(const v8u*)(vs + 8);
            vr2 = *(const v8u*)(vs + 16); vr3 = *(const v8u*)(vs + 24);
            if (tid < 32) areg = a_g[h * SEQ + s0 + tid];
        }

        // P @ V (hi + lo): wave w owns output cols [w*64, w*64+64)
        v8h aH0 = *(const v8h*)&P_lds[l15][qd * 8];
        v8h aH1 = *(const v8h*)&P_lds[16 + l15][qd * 8];
        v8h aL0 = *(const v8h*)&Plo_lds[l15][qd * 8];
        v8h aL1 = *(const v8h*)&Plo_lds[16 + l15][qd * 8];
#pragma unroll
        for (int nn = 0; nn < 4; nn++) {
            v8h bV = *(const v8h*)&vT_lds[w * 64 + nn * 16 + l15][qd * 8];
            acc[0][nn] = __builtin_amdgcn_mfma_f32_16x16x32_f16(aH0, bV, acc[0][nn], 0, 0, 0);
            acc[0][nn] = __builtin_amdgcn_mfma_f32_16x16x32_f16(aL0, bV, acc[0][nn], 0, 0, 0);
            acc[1][nn] = __builtin_amdgcn_mfma_f32_16x16x32_f16(aH1, bV, acc[1][nn], 0, 0, 0);
            acc[1][nn] = __builtin_amdgcn_mfma_f32_16x16x32_f16(aL1, bV, acc[1][nn], 0, 0, 0);
        }
        if (w == 3) {   // ones-column trick: row normalizer (hi+lo)
            v8h bN = *(const v8h*)&vT_lds[256 + l15][qd * 8];
            accN[0] = __builtin_amdgcn_mfma_f32_16x16x32_f16(aH0, bN, accN[0], 0, 0, 0);
            accN[0] = __builtin_amdgcn_mfma_f32_16x16x32_f16(aL0, bN, accN[0], 0, 0, 0);
            accN[1] = __builtin_amdgcn_mfma_f32_16x16x32_f16(aH1, bN, accN[1], 0, 0, 0);
            accN[1] = __builtin_amdgcn_mfma_f32_16x16x32_f16(aL1, bN, accN[1], 0, 0, 0);
        }

        // flush at tile end or quota end (raw partials; fire-and-forget atomics)
        if (js == tile || remaining == 1) {
#pragma unroll
            for (int m = 0; m < 2; m++)
#pragma unroll
                for (int r = 0; r < 4; r++) {
                    int row = t0 + m * 16 + qd * 4 + r;
#pragma unroll
                    for (int nn = 0; nn < 4; nn++) {
                        int col = hd0 + w * 64 + nn * 16 + l15;
                        atomicAdd(&h_buf[(size_t)row * DMODEL + col], acc[m][nn][r]);
                        acc[m][nn][r] = 0.f;
                    }
                    if (w == 3 && l15 == 0)
                        atomicAdd(&rs_buf[h * SEQ + row], accN[m][r]);
                    accN[m][r] = 0.f;
                }
        }
        if (--remaining == 0) break;
        tile = ntile; js = njs; needQ = nq;
    }
}

// ------------------------------------- finish: normalizer scale + per-head LN
// (round-10/16 verbatim)
__global__ __launch_bounds__(256) void k_finish(const float* __restrict__ h_buf,
                                                const float* __restrict__ rs_buf,
                                                const float* __restrict__ nfl_g,
                                                const void* __restrict__ ow,
                                                const int* flag, void* out) {
    const int wv = threadIdx.x >> 6, lane = threadIdx.x & 63;
    const int rid = blockIdx.x * 4 + wv;       // 0..16383
    const int s = rid >> 3, h = rid & 7;
    const int bf = *(volatile const int*)flag;
    float rs  = rs_buf[h * SEQ + s];
    float nfl = nfl_g[h * SEQ + s];
    float sc  = 1.0f / (fmaxf(fabsf(rs), nfl) + 1e-6f);
    size_t base = (size_t)s * DMODEL + h * DHEAD + lane * 4;
    v4f hv = *(const v4f*)(h_buf + base);
#pragma unroll
    for (int j = 0; j < 4; j++) hv[j] *= sc;
    float sm = hv[0] + hv[1] + hv[2] + hv[3];
    float sq = hv[0] * hv[0] + hv[1] * hv[1] + hv[2] * hv[2] + hv[3] * hv[3];
#pragma unroll
    for (int m = 1; m < 64; m <<= 1) {
        sm += __shfl_xor(sm, m, 64);
        sq += __shfl_xor(sq, m, 64);
    }
    float mean = sm * (1.0f / 256.0f);
    float var  = fmaxf(sq * (1.0f / 256.0f) - mean * mean, 0.0f);
    float rstd = rsqrtf(var + 1e-6f);
    int gi = h * DHEAD + lane * 4;
    float gv[4];
    if (bf) {
        const unsigned short* gp = (const unsigned short*)ow;
#pragma unroll
        for (int j = 0; j < 4; j++) gv[j] = b2f(gp[gi + j]);
    } else {
        const float* gp = (const float*)ow;
#pragma unroll
        for (int j = 0; j < 4; j++) gv[j] = gp[gi + j];
    }
    if (bf) {
        unsigned short* o = (unsigned short*)out + base;
#pragma unroll
        for (int j = 0; j < 4; j++) o[j] = f2b((hv[j] - mean) * rstd * gv[j]);
    } else {
        float* o = (float*)out + base;
#pragma unroll
        for (int j = 0; j < 4; j++) o[j] = (hv[j] - mean) * rstd * gv[j];
    }
}

// ---------------------------------------------------------------------- host
extern "C" void kernel_launch(void* const* d_in, const int* in_sizes, int n_in,
                              void* d_out, int out_size, void* d_ws, size_t ws_size,
                              hipStream_t stream) {
    const void* q   = d_in[0];
    const void* k   = d_in[1];
    const void* v   = d_in[2];
    const void* igk = d_in[3];
    const void* igb = d_in[4];
    const void* fgk = d_in[5];
    const void* fgb = d_in[6];
    const void* ow  = d_in[7];

    char* ws = (char*)d_ws;
    int*   flag   = (int*)(ws + 0);
    float* iparts = (float*)(ws + 1024);                       // 16*8*2048 f32 = 1 MiB
    float* fparts = iparts + 16 * NHEAD * SEQ;
    float* a_g    = fparts + 16 * NHEAD * SEQ;
    float* amax_g = a_g + NHEAD * SEQ;
    float* nfl_g  = amax_g + NHEAD * SEQ;
    // zeroed-by-k_pre region (contiguous): rs_buf | h_buf
    float* rs_buf = nfl_g + NHEAD * SEQ;
    float* h_buf  = rs_buf + NHEAD * SEQ;
    unsigned short* qb = (unsigned short*)(h_buf + (size_t)SEQ * DMODEL);
    unsigned short* kb = qb + (size_t)SEQ * DMODEL;
    unsigned short* vT = kb + (size_t)SEQ * DMODEL;

    // 4 graph nodes, no memset
    k_pre<<<3584, 256, 0, stream>>>(q, k, v, igk, fgk, flag, qb, kb, vT, iparts, fparts, rs_buf);
    k_scan<<<8, 256, 0, stream>>>(iparts, fparts, igb, fgb, flag, a_g, amax_g, nfl_g);
    k_main<<<dim3(8, 96), 256, 0, stream>>>(qb, kb, vT, a_g, amax_g, h_buf, rs_buf);
    k_finish<<<4096, 256, 0, stream>>>(h_buf, rs_buf, nfl_g, ow, flag, d_out);
}